// Round 13
// baseline (749.438 us; speedup 1.0000x reference)
//
#include <hip/hip_runtime.h>
#include <math.h>

#define N_NODES 50000
#define N_EDGES 640000
#define HID 128
#define NL 3
#define NGRAPHS 64
#define NT 4096
#define TPTS 8
#define DMAX 1.7330f
#define NPAD 50176   // 196*256
#define NWT8 6250    // 50000/8 wave-tiles
#define GRID_F 1563  // ceil(6250/4)

typedef __attribute__((ext_vector_type(8))) short bf16x8;
typedef __attribute__((ext_vector_type(4))) float f32x4;

// ---------------- module-scope device buffers -------------------------------
__device__ __align__(16) float g_h  [N_NODES * HID];           // f32 node features
__device__ __align__(16) unsigned short g_xfb [N_NODES * HID]; // bf16 xf
__device__ __align__(16) unsigned short g_aggb[N_NODES * HID]; // bf16 aggregation
__device__ __align__(16) float g_table[NL * NT * HID];         // W(d)*C(d), 6 MB
__device__ __align__(16) unsigned short g_wT[9 * HID * HID];   // bf16 [n][k]
__device__ __align__(16) int   g_cnt[NPAD];
__device__ __align__(16) int   g_ex [NPAD];
__device__ __align__(16) int   g_row[NPAD];
__device__ __align__(16) int   g_part[256];
__device__ __align__(16) int   g_ssrc[N_EDGES];
__device__ __align__(16) int   g_sidx[N_EDGES];                // nearest table idx
__device__ __align__(16) float g_sx  [N_NODES];                // e_atom (head)
__device__ __align__(16) float g_gout[NGRAPHS];

__device__ __forceinline__ unsigned short f2bfbits(float x){
    union { float f; unsigned int i; } v; v.f = x;
    unsigned int lsb = (v.i >> 16) & 1;
    v.i += 0x7fff + lsb;                      // RNE to bf16
    return (unsigned short)(v.i >> 16);
}
__device__ __forceinline__ float bf2f(unsigned short u){
    union { unsigned int i; float f; } v; v.i = ((unsigned int)u) << 16; return v.f;
}
__device__ __forceinline__ float sspf(float x){
    return fmaxf(x, 0.0f) + log1pf(__expf(-fabsf(x))) - 0.69314718055994530942f;
}

// ---------------- counting sort of edges by dst ------------------------------
__global__ __launch_bounds__(256) void zero_cnt_kernel(){
    int i = blockIdx.x * 256 + threadIdx.x;
    g_cnt[i] = 0;                                   // NPAD exact
    if (blockIdx.x == 0 && threadIdx.x < NGRAPHS) g_gout[threadIdx.x] = 0.0f;
}
__global__ __launch_bounds__(256) void hist_kernel(const int* __restrict__ dst){
    int e = blockIdx.x * 256 + threadIdx.x;         // 2500*256 exact
    atomicAdd(&g_cnt[dst[e]], 1);
}
__global__ __launch_bounds__(256) void scan1_kernel(){
    __shared__ int s[256];
    int b = blockIdx.x, t = threadIdx.x, i = b * 256 + t;
    int c = g_cnt[i];
    s[t] = c; __syncthreads();
    #pragma unroll
    for (int off = 1; off < 256; off <<= 1){
        int v = (t >= off) ? s[t - off] : 0; __syncthreads();
        s[t] += v; __syncthreads();
    }
    g_ex[i] = s[t] - c;
    if (t == 255) g_part[b] = s[255];
}
__global__ __launch_bounds__(256) void scan2_kernel(){
    __shared__ int s[256];
    int t = threadIdx.x;
    s[t] = (t < 196) ? g_part[t] : 0; __syncthreads();
    #pragma unroll
    for (int off = 1; off < 256; off <<= 1){
        int v = (t >= off) ? s[t - off] : 0; __syncthreads();
        s[t] += v; __syncthreads();
    }
    g_part[t] = s[t];
}
__global__ __launch_bounds__(256) void scan3_kernel(){
    int b = blockIdx.x, i = b * 256 + threadIdx.x;
    g_row[i] = g_ex[i] + (b > 0 ? g_part[b - 1] : 0);
}
__global__ __launch_bounds__(256) void scatter_kernel(
    const float* __restrict__ pos, const int* __restrict__ src,
    const int* __restrict__ dst)
{
    int e = blockIdx.x * 256 + threadIdx.x;         // exact
    int sv = src[e], dv = dst[e];
    float dx = pos[3*dv]   - pos[3*sv];
    float dy = pos[3*dv+1] - pos[3*sv+1];
    float dz = pos[3*dv+2] - pos[3*sv+2];
    float d = sqrtf(dx*dx + dy*dy + dz*dz);         // < sqrt(3) < DMAX
    int p = atomicAdd(&g_row[dv], 1);               // g_row[v] ends at end-offset
    g_ssrc[p] = sv;
    g_sidx[p] = (int)(d * ((float)(NT - 1) / DMAX) + 0.5f);  // nearest
}

// ---------------- per-layer filter table: 8 points/block, w2 row-reuse ------
__global__ __launch_bounds__(128) void table_kernel(
    const float* __restrict__ w1g, const float* __restrict__ b1g,
    const float* __restrict__ w2g, const float* __restrict__ b2g)
{
    int bid = blockIdx.x;                           // 3 * NT/TPTS blocks
    int l = bid / (NT / TPTS);
    int pt0 = (bid % (NT / TPTS)) * TPTS;
    int n = threadIdx.x;
    __shared__ __align__(16) float w1s[50 * 128];   // 25.6 KB
    __shared__ float ea[TPTS][50];
    __shared__ float tm[TPTS][128];
    __shared__ float Cv[TPTS];
    for (int i = n; i < 50 * 128; i += 128) w1s[i] = w1g[(size_t)l * 50 * 128 + i];
    if (n < 50){
        const float step = 5.0f / 49.0f;
        #pragma unroll
        for (int p = 0; p < TPTS; p++){
            float d = (pt0 + p) * (DMAX / (float)(NT - 1));
            float srel = d * 0.2f;
            float env = expf(1.0f - 1.0f / (1.0f - srel * srel));
            float dd = d - step * (float)n;
            ea[p][n] = expf((-0.5f / (step * step)) * dd * dd) * env;
        }
    }
    if (n < TPTS){
        float d = (pt0 + n) * (DMAX / (float)(NT - 1));
        Cv[n] = 0.5f * (cosf(d * 0.62831853071795864769f) + 1.0f);
    }
    __syncthreads();
    float b1v = b1g[l * 128 + n];
    #pragma unroll
    for (int p = 0; p < TPTS; p++){
        float acc = b1v;
        #pragma unroll 10
        for (int k = 0; k < 50; k++) acc = fmaf(ea[p][k], w1s[k * 128 + n], acc);
        tm[p][n] = sspf(acc);
    }
    __syncthreads();
    float b2v = b2g[l * 128 + n];
    float acc2[TPTS];
    #pragma unroll
    for (int p = 0; p < TPTS; p++) acc2[p] = b2v;
    const float* w2 = w2g + (size_t)l * 128 * 128;
    for (int k = 0; k < 128; k++){
        float wv = w2[k * 128 + n];                 // 1 global read, 8 FMA reuse
        #pragma unroll
        for (int p = 0; p < TPTS; p++) acc2[p] = fmaf(tm[p][k], wv, acc2[p]);
    }
    #pragma unroll
    for (int p = 0; p < TPTS; p++)
        g_table[((size_t)l * NT + pt0 + p) * 128 + n] = acc2[p] * Cv[p];
}

// ---------------- weight prep: bf16 transpose of 9 node matrices ------------
__global__ __launch_bounds__(256) void wprep_kernel(
    const float* __restrict__ c1, const float* __restrict__ c2,
    const float* __restrict__ lwp)
{
    int gid = blockIdx.x * 256 + threadIdx.x;       // 576*256 = 147456 exact
    int mat = gid >> 14, r = gid & 16383;
    int n = r & 127, k = r >> 7;
    int l = mat / 3, w = mat % 3;
    const float* base = (w == 0 ? c1 : w == 1 ? c2 : lwp) + (size_t)l * HID * HID;
    g_wT[(size_t)mat * HID * HID + n * 128 + k] = f2bfbits(base[k * 128 + n]);
}

// ---------------- conv1 (layer 0): wave-autonomous, no LDS ------------------
// per 8-node wave-tile: h init from emb + xfb = bf16(emb[z]) @ c1(l0)
__global__ __launch_bounds__(256) void conv1_kernel(
    const int* __restrict__ z, const float* __restrict__ emb)
{
    int tid = threadIdx.x;
    int wave = tid >> 6, lane = tid & 63, quad = lane >> 4, l16 = lane & 15;
    int wt = blockIdx.x * 4 + wave;
    if (wt >= NWT8) return;
    int base = wt * 8;
    int ar = base + l16; if (ar > N_NODES - 1) ar = N_NODES - 1;   // rows 8..15 junk
    int zr = z[ar];

    // h init (rows 0..7 only, vectorized 32B per work item)
    for (int i = lane; i < 128; i += 64){
        int row = i >> 4, c = i & 15;
        int node = base + row;                       // <= 49999 always
        int zv = z[node];
        const float* p = &emb[(size_t)zv * 128 + c * 8];
        *(float4*)&g_h[(size_t)node * 128 + c * 8]     = *(const float4*)p;
        *(float4*)&g_h[(size_t)node * 128 + c * 8 + 4] = *(const float4*)(p + 4);
    }

    // A fragments straight from emb
    bf16x8 av[4];
    #pragma unroll
    for (int ks = 0; ks < 4; ks++){
        const float* p = &emb[(size_t)zr * 128 + ks * 32 + quad * 8];
        float4 f0 = *(const float4*)p;
        float4 f1 = *(const float4*)(p + 4);
        union { unsigned int u[4]; bf16x8 v; } pk;
        pk.u[0] = (unsigned int)f2bfbits(f0.x) | ((unsigned int)f2bfbits(f0.y) << 16);
        pk.u[1] = (unsigned int)f2bfbits(f0.z) | ((unsigned int)f2bfbits(f0.w) << 16);
        pk.u[2] = (unsigned int)f2bfbits(f1.x) | ((unsigned int)f2bfbits(f1.y) << 16);
        pk.u[3] = (unsigned int)f2bfbits(f1.z) | ((unsigned int)f2bfbits(f1.w) << 16);
        av[ks] = pk.v;
    }
    f32x4 acc[8] = {};
    #pragma unroll
    for (int nt = 0; nt < 8; nt++){
        int n = nt * 16 + l16;
        #pragma unroll
        for (int ks = 0; ks < 4; ks++){
            bf16x8 bv = *(const bf16x8*)&g_wT[n * 128 + ks * 32 + quad * 8];
            acc[nt] = __builtin_amdgcn_mfma_f32_16x16x32_bf16(av[ks], bv, acc[nt], 0, 0, 0);
        }
    }
    #pragma unroll
    for (int nt = 0; nt < 8; nt++){
        int col = nt * 16 + l16;
        #pragma unroll
        for (int r = 0; r < 4; r++){
            int row = quad * 4 + r;
            if (row < 8)
                g_xfb[(size_t)(base + row) * 128 + col] = f2bfbits(acc[nt][r]);
        }
    }
}

// ---------------- wave-autonomous fused GEMM chain (8-node tiles) -----------
__global__ __launch_bounds__(256) void fused_kernel(
    int l, const float* __restrict__ bias2, const float* __restrict__ biasl,
    int skip3)
{
    __shared__ __align__(16) unsigned short t_sl[4][16 * 128];  // 16 KB
    int tid = threadIdx.x;
    int wave = tid >> 6, lane = tid & 63, quad = lane >> 4, l16 = lane & 15;
    const unsigned short* c2  = g_wT + (size_t)(l * 3 + 1) * HID * HID;
    const unsigned short* lw  = g_wT + (size_t)(l * 3 + 2) * HID * HID;
    const unsigned short* c1n = g_wT + (size_t)((l + 1) * 3) * HID * HID;
    unsigned short* ts = t_sl[wave];

    int wt = blockIdx.x * 4 + wave;
    if (wt >= NWT8) return;
    int base = wt * 8;
    int ar = base + l16; if (ar > N_NODES - 1) ar = N_NODES - 1;   // rows 8..15 junk

    float b2r[8], blr[8];
    #pragma unroll
    for (int nt = 0; nt < 8; nt++){
        b2r[nt] = bias2[nt * 16 + l16];
        blr[nt] = biasl[nt * 16 + l16];
    }

    // ---- GEMM1: acc = aggb(tile) @ c2   (A direct from global, B from L2)
    bf16x8 av[4];
    #pragma unroll
    for (int ks = 0; ks < 4; ks++)
        av[ks] = *(const bf16x8*)&g_aggb[(size_t)ar * 128 + ks * 32 + quad * 8];
    f32x4 acc[8] = {};
    #pragma unroll
    for (int nt = 0; nt < 8; nt++){
        int n = nt * 16 + l16;
        #pragma unroll
        for (int ks = 0; ks < 4; ks++){
            bf16x8 bv = *(const bf16x8*)&c2[n * 128 + ks * 32 + quad * 8];
            acc[nt] = __builtin_amdgcn_mfma_f32_16x16x32_bf16(av[ks], bv, acc[nt], 0, 0, 0);
        }
    }
    // epilogue1: t = ssp(acc + b2) -> ts rows 0..7 (swizzled)
    #pragma unroll
    for (int nt = 0; nt < 8; nt++){
        int col = nt * 16 + l16;
        int c = col >> 3, sub = col & 7;
        #pragma unroll
        for (int r = 0; r < 4; r++){
            int row = quad * 4 + r;
            if (row < 8)
                ts[row * 128 + ((c ^ row) & 15) * 8 + sub] =
                    f2bfbits(sspf(acc[nt][r] + b2r[nt]));
        }
    }

    // ---- GEMM2: acc2 = t @ lw   (A rows 8..15 junk, discarded)
    #pragma unroll
    for (int ks = 0; ks < 4; ks++){
        int phys = ((ks * 4 + quad) ^ l16) & 15;
        av[ks] = *(const bf16x8*)&ts[l16 * 128 + phys * 8];
    }
    f32x4 acc2[8] = {};
    #pragma unroll
    for (int nt = 0; nt < 8; nt++){
        int n = nt * 16 + l16;
        #pragma unroll
        for (int ks = 0; ks < 4; ks++){
            bf16x8 bv = *(const bf16x8*)&lw[n * 128 + ks * 32 + quad * 8];
            acc2[nt] = __builtin_amdgcn_mfma_f32_16x16x32_bf16(av[ks], bv, acc2[nt], 0, 0, 0);
        }
    }
    // epilogue2: h += acc2 + lb; stash bf16(h) into ts for GEMM3
    #pragma unroll
    for (int nt = 0; nt < 8; nt++){
        int col = nt * 16 + l16;
        int c = col >> 3, sub = col & 7;
        #pragma unroll
        for (int r = 0; r < 4; r++){
            int row = quad * 4 + r;
            if (row < 8){
                size_t o = (size_t)(base + row) * 128 + col;
                float hv = g_h[o] + acc2[nt][r] + blr[nt];
                g_h[o] = hv;
                if (!skip3)
                    ts[row * 128 + ((c ^ row) & 15) * 8 + sub] = f2bfbits(hv);
            }
        }
    }
    if (skip3) return;

    // ---- GEMM3: xfb = bf16(h) @ c1next
    #pragma unroll
    for (int ks = 0; ks < 4; ks++){
        int phys = ((ks * 4 + quad) ^ l16) & 15;
        av[ks] = *(const bf16x8*)&ts[l16 * 128 + phys * 8];
    }
    f32x4 acc3[8] = {};
    #pragma unroll
    for (int nt = 0; nt < 8; nt++){
        int n = nt * 16 + l16;
        #pragma unroll
        for (int ks = 0; ks < 4; ks++){
            bf16x8 bv = *(const bf16x8*)&c1n[n * 128 + ks * 32 + quad * 8];
            acc3[nt] = __builtin_amdgcn_mfma_f32_16x16x32_bf16(av[ks], bv, acc3[nt], 0, 0, 0);
        }
    }
    #pragma unroll
    for (int nt = 0; nt < 8; nt++){
        int col = nt * 16 + l16;
        #pragma unroll
        for (int r = 0; r < 4; r++){
            int row = quad * 4 + r;
            if (row < 8)
                g_xfb[(size_t)(base + row) * 128 + col] = f2bfbits(acc3[nt][r]);
        }
    }
}

// ---------------- CSR edge aggregation: nearest-table, 4-edge unroll --------
__global__ __launch_bounds__(256) void agg_kernel(int l){
    const float* __restrict__ T = g_table + (size_t)l * NT * 128;
    int tid = threadIdx.x;
    int grp = tid >> 5, n0 = (tid & 31) * 4;
    int v = blockIdx.x * 8 + grp;                   // 6250 blocks * 8 = 50000 exact
    int e1 = g_row[v];
    int e0 = e1 - g_cnt[v];
    float a0 = 0.f, a1 = 0.f, a2 = 0.f, a3 = 0.f;
    int j = e0;
    for (; j + 4 <= e1; j += 4){
        int sA = g_ssrc[j],   sB = g_ssrc[j+1];
        int sC = g_ssrc[j+2], sD = g_ssrc[j+3];
        int iA = g_sidx[j],   iB = g_sidx[j+1];
        int iC = g_sidx[j+2], iD = g_sidx[j+3];
        float4 tA = *(const float4*)&T[(size_t)iA * 128 + n0];
        float4 tB = *(const float4*)&T[(size_t)iB * 128 + n0];
        float4 tC = *(const float4*)&T[(size_t)iC * 128 + n0];
        float4 tD = *(const float4*)&T[(size_t)iD * 128 + n0];
        ushort4 gA = *(const ushort4*)&g_xfb[(size_t)sA * 128 + n0];
        ushort4 gB = *(const ushort4*)&g_xfb[(size_t)sB * 128 + n0];
        ushort4 gC = *(const ushort4*)&g_xfb[(size_t)sC * 128 + n0];
        ushort4 gD = *(const ushort4*)&g_xfb[(size_t)sD * 128 + n0];
        a0 = fmaf(tA.x, bf2f(gA.x), a0); a1 = fmaf(tA.y, bf2f(gA.y), a1);
        a2 = fmaf(tA.z, bf2f(gA.z), a2); a3 = fmaf(tA.w, bf2f(gA.w), a3);
        a0 = fmaf(tB.x, bf2f(gB.x), a0); a1 = fmaf(tB.y, bf2f(gB.y), a1);
        a2 = fmaf(tB.z, bf2f(gB.z), a2); a3 = fmaf(tB.w, bf2f(gB.w), a3);
        a0 = fmaf(tC.x, bf2f(gC.x), a0); a1 = fmaf(tC.y, bf2f(gC.y), a1);
        a2 = fmaf(tC.z, bf2f(gC.z), a2); a3 = fmaf(tC.w, bf2f(gC.w), a3);
        a0 = fmaf(tD.x, bf2f(gD.x), a0); a1 = fmaf(tD.y, bf2f(gD.y), a1);
        a2 = fmaf(tD.z, bf2f(gD.z), a2); a3 = fmaf(tD.w, bf2f(gD.w), a3);
    }
    for (; j < e1; j++){
        int s = g_ssrc[j], i0 = g_sidx[j];
        float4 t0 = *(const float4*)&T[(size_t)i0 * 128 + n0];
        ushort4 g = *(const ushort4*)&g_xfb[(size_t)s * 128 + n0];
        a0 = fmaf(t0.x, bf2f(g.x), a0); a1 = fmaf(t0.y, bf2f(g.y), a1);
        a2 = fmaf(t0.z, bf2f(g.z), a2); a3 = fmaf(t0.w, bf2f(g.w), a3);
    }
    ushort4 o;
    o.x = f2bfbits(a0); o.y = f2bfbits(a1); o.z = f2bfbits(a2); o.w = f2bfbits(a3);
    *(ushort4*)&g_aggb[(size_t)v * 128 + n0] = o;
}

// ---------------- output head: per-node energy (no atomics) -----------------
__global__ __launch_bounds__(256) void head_kernel(
    const float* __restrict__ w1g, const float* __restrict__ b1g,
    const float* __restrict__ w2g, const float* __restrict__ b2g)
{
    __shared__ __align__(16) float w1h[128 * 64];   // 32 KB
    __shared__ __align__(16) float w2h[64];
    __shared__ __align__(16) float b1h[64];
    __shared__ __align__(16) float hrow[4][128];
    int tid = threadIdx.x;
    for (int i = tid; i < 128 * 64 / 4; i += 256)
        *(float4*)&w1h[i * 4] = *(const float4*)&w1g[i * 4];
    if (tid < 64){ w2h[tid] = w2g[tid]; b1h[tid] = b1g[tid]; }
    float sb2 = b2g[0];
    __syncthreads();
    int wave = tid >> 6, lane = tid & 63;
    for (int nb = blockIdx.x * 4; nb < N_NODES; nb += gridDim.x * 4){
        int node = nb + wave;
        __syncthreads();
        if (node < N_NODES){
            hrow[wave][lane]      = g_h[(size_t)node * 128 + lane];
            hrow[wave][64 + lane] = g_h[(size_t)node * 128 + 64 + lane];
        }
        __syncthreads();
        if (node < N_NODES){
            float acc = b1h[lane];
            #pragma unroll 8
            for (int k = 0; k < 128; k++)
                acc = fmaf(hrow[wave][k], w1h[k * 64 + lane], acc);
            acc = sspf(acc) * w2h[lane];
            #pragma unroll
            for (int off = 32; off > 0; off >>= 1) acc += __shfl_down(acc, off, 64);
            if (lane == 0) g_sx[node] = acc + sb2;
        }
    }
}

// ---------------- segment-sum of e_atom with LDS pre-reduction --------------
__global__ __launch_bounds__(256) void reduce_kernel(const int* __restrict__ batch){
    __shared__ float part[NGRAPHS];
    int tid = threadIdx.x;
    if (tid < NGRAPHS) part[tid] = 0.0f;
    __syncthreads();
    int i = blockIdx.x * 256 + tid;                 // 196 blocks
    if (i < N_NODES) atomicAdd(&part[batch[i]], g_sx[i]);
    __syncthreads();
    if (tid < NGRAPHS && part[tid] != 0.0f)
        __hip_atomic_fetch_add(&g_gout[tid], part[tid],
                               __ATOMIC_RELAXED, __HIP_MEMORY_SCOPE_AGENT);
}

__global__ void store_kernel(float* __restrict__ out){
    int i = threadIdx.x;
    if (i < NGRAPHS) out[i] = g_gout[i];
}

extern "C" void kernel_launch(void* const* d_in, const int* in_sizes, int n_in,
                              void* d_out, int out_size, void* d_ws, size_t ws_size,
                              hipStream_t stream)
{
    const int* z       = (const int*)d_in[0];
    const float* pos   = (const float*)d_in[1];
    const int* ei      = (const int*)d_in[2];
    const int* src = ei;
    const int* dst = ei + N_EDGES;
    const int* batch   = (const int*)d_in[3];
    const float* emb     = (const float*)d_in[4];
    const float* mlp_w1  = (const float*)d_in[5];
    const float* mlp_b1  = (const float*)d_in[6];
    const float* mlp_w2  = (const float*)d_in[7];
    const float* mlp_b2  = (const float*)d_in[8];
    const float* conv1_w = (const float*)d_in[9];
    const float* conv2_w = (const float*)d_in[10];
    const float* conv2_b = (const float*)d_in[11];
    const float* lin_w   = (const float*)d_in[12];
    const float* lin_b   = (const float*)d_in[13];
    const float* out1_w  = (const float*)d_in[14];
    const float* out1_b  = (const float*)d_in[15];
    const float* out2_w  = (const float*)d_in[16];
    const float* out2_b  = (const float*)d_in[17];
    (void)d_ws; (void)ws_size; (void)in_sizes; (void)n_in; (void)out_size;

    // --- one-time: CSR sort, tables, weight prep ---
    zero_cnt_kernel<<<196, 256, 0, stream>>>();
    hist_kernel<<<2500, 256, 0, stream>>>(dst);
    scan1_kernel<<<196, 256, 0, stream>>>();
    scan2_kernel<<<1, 256, 0, stream>>>();
    scan3_kernel<<<196, 256, 0, stream>>>();
    scatter_kernel<<<2500, 256, 0, stream>>>(pos, src, dst);
    table_kernel<<<NL * (NT / TPTS), 128, 0, stream>>>(mlp_w1, mlp_b1, mlp_w2, mlp_b2);
    wprep_kernel<<<576, 256, 0, stream>>>(conv1_w, conv2_w, lin_w);

    conv1_kernel<<<GRID_F, 256, 0, stream>>>(z, emb);  // h init + layer-0 conv1
    for (int l = 0; l < NL; l++){
        agg_kernel<<<6250, 256, 0, stream>>>(l);
        fused_kernel<<<GRID_F, 256, 0, stream>>>(l, conv2_b + (size_t)l * HID,
                                                 lin_b + (size_t)l * HID, l == NL - 1);
    }

    head_kernel<<<512, 256, 0, stream>>>(out1_w, out1_b, out2_w, out2_b);
    reduce_kernel<<<196, 256, 0, stream>>>(batch);
    store_kernel<<<1, 64, 0, stream>>>((float*)d_out);
}

// Round 14
// 601.265 us; speedup vs baseline: 1.2464x; 1.2464x over previous
//
#include <hip/hip_runtime.h>
#include <math.h>

#define N_NODES 50000
#define N_EDGES 640000
#define HID 128
#define NL 3
#define NGRAPHS 64
#define NT 4096
#define TPTS 8
#define DMAX 1.7330f
#define NPAD 50176   // 196*256
#define NTILES 1563  // ceil(50000/32)
#define NWT 3125     // 50000/16 wave-tiles

typedef __attribute__((ext_vector_type(8))) short bf16x8;
typedef __attribute__((ext_vector_type(4))) float f32x4;

// ---------------- module-scope device buffers -------------------------------
__device__ __align__(16) float g_h  [N_NODES * HID];           // f32 node features
__device__ __align__(16) unsigned short g_xfb [N_NODES * HID]; // bf16 xf
__device__ __align__(16) unsigned short g_aggb[N_NODES * HID]; // bf16 aggregation
__device__ __align__(16) float g_table[NL * NT * HID];         // W(d)*C(d), 6 MB
__device__ __align__(16) unsigned short g_wT[9 * HID * HID];   // bf16 [n][k]
__device__ __align__(16) int   g_cnt[NPAD];
__device__ __align__(16) int   g_ex [NPAD];
__device__ __align__(16) int   g_row[NPAD];
__device__ __align__(16) int   g_part[256];
__device__ __align__(16) int   g_ssrc[N_EDGES];
__device__ __align__(16) int   g_sidx[N_EDGES];                // nearest table idx
__device__ __align__(16) float g_gout[NGRAPHS];

__device__ __forceinline__ unsigned short f2bfbits(float x){
    union { float f; unsigned int i; } v; v.f = x;
    unsigned int lsb = (v.i >> 16) & 1;
    v.i += 0x7fff + lsb;                      // RNE to bf16
    return (unsigned short)(v.i >> 16);
}
__device__ __forceinline__ float bf2f(unsigned short u){
    union { unsigned int i; float f; } v; v.i = ((unsigned int)u) << 16; return v.f;
}
__device__ __forceinline__ float sspf(float x){
    return fmaxf(x, 0.0f) + log1pf(__expf(-fabsf(x))) - 0.69314718055994530942f;
}

// ---------------- counting sort of edges by dst ------------------------------
__global__ __launch_bounds__(256) void zero_cnt_kernel(){
    int i = blockIdx.x * 256 + threadIdx.x;
    g_cnt[i] = 0;                                   // NPAD exact
    if (blockIdx.x == 0 && threadIdx.x < NGRAPHS) g_gout[threadIdx.x] = 0.0f;
}
__global__ __launch_bounds__(256) void hist_kernel(const int* __restrict__ dst){
    int e = blockIdx.x * 256 + threadIdx.x;         // 2500*256 exact
    atomicAdd(&g_cnt[dst[e]], 1);
}
__global__ __launch_bounds__(256) void scan1_kernel(){
    __shared__ int s[256];
    int b = blockIdx.x, t = threadIdx.x, i = b * 256 + t;
    int c = g_cnt[i];
    s[t] = c; __syncthreads();
    #pragma unroll
    for (int off = 1; off < 256; off <<= 1){
        int v = (t >= off) ? s[t - off] : 0; __syncthreads();
        s[t] += v; __syncthreads();
    }
    g_ex[i] = s[t] - c;
    if (t == 255) g_part[b] = s[255];
}
__global__ __launch_bounds__(256) void scan2_kernel(){
    __shared__ int s[256];
    int t = threadIdx.x;
    s[t] = (t < 196) ? g_part[t] : 0; __syncthreads();
    #pragma unroll
    for (int off = 1; off < 256; off <<= 1){
        int v = (t >= off) ? s[t - off] : 0; __syncthreads();
        s[t] += v; __syncthreads();
    }
    g_part[t] = s[t];
}
__global__ __launch_bounds__(256) void scan3_kernel(){
    int b = blockIdx.x, i = b * 256 + threadIdx.x;
    g_row[i] = g_ex[i] + (b > 0 ? g_part[b - 1] : 0);
}
__global__ __launch_bounds__(256) void scatter_kernel(
    const float* __restrict__ pos, const int* __restrict__ src,
    const int* __restrict__ dst)
{
    int e = blockIdx.x * 256 + threadIdx.x;         // exact
    int sv = src[e], dv = dst[e];
    float dx = pos[3*dv]   - pos[3*sv];
    float dy = pos[3*dv+1] - pos[3*sv+1];
    float dz = pos[3*dv+2] - pos[3*sv+2];
    float d = sqrtf(dx*dx + dy*dy + dz*dz);         // < sqrt(3) < DMAX
    int p = atomicAdd(&g_row[dv], 1);               // g_row[v] ends at end-offset
    g_ssrc[p] = sv;
    g_sidx[p] = (int)(d * ((float)(NT - 1) / DMAX) + 0.5f);  // nearest
}

// ---------------- per-layer filter table: 8 points/block, w2 row-reuse ------
__global__ __launch_bounds__(128) void table_kernel(
    const float* __restrict__ w1g, const float* __restrict__ b1g,
    const float* __restrict__ w2g, const float* __restrict__ b2g)
{
    int bid = blockIdx.x;                           // 3 * NT/TPTS blocks
    int l = bid / (NT / TPTS);
    int pt0 = (bid % (NT / TPTS)) * TPTS;
    int n = threadIdx.x;
    __shared__ __align__(16) float w1s[50 * 128];   // 25.6 KB
    __shared__ float ea[TPTS][50];
    __shared__ float tm[TPTS][128];
    __shared__ float Cv[TPTS];
    for (int i = n; i < 50 * 128; i += 128) w1s[i] = w1g[(size_t)l * 50 * 128 + i];
    if (n < 50){
        const float step = 5.0f / 49.0f;
        #pragma unroll
        for (int p = 0; p < TPTS; p++){
            float d = (pt0 + p) * (DMAX / (float)(NT - 1));
            float srel = d * 0.2f;
            float env = expf(1.0f - 1.0f / (1.0f - srel * srel));
            float dd = d - step * (float)n;
            ea[p][n] = expf((-0.5f / (step * step)) * dd * dd) * env;
        }
    }
    if (n < TPTS){
        float d = (pt0 + n) * (DMAX / (float)(NT - 1));
        Cv[n] = 0.5f * (cosf(d * 0.62831853071795864769f) + 1.0f);
    }
    __syncthreads();
    float b1v = b1g[l * 128 + n];
    #pragma unroll
    for (int p = 0; p < TPTS; p++){
        float acc = b1v;
        #pragma unroll 10
        for (int k = 0; k < 50; k++) acc = fmaf(ea[p][k], w1s[k * 128 + n], acc);
        tm[p][n] = sspf(acc);
    }
    __syncthreads();
    float b2v = b2g[l * 128 + n];
    float acc2[TPTS];
    #pragma unroll
    for (int p = 0; p < TPTS; p++) acc2[p] = b2v;
    const float* w2 = w2g + (size_t)l * 128 * 128;
    for (int k = 0; k < 128; k++){
        float wv = w2[k * 128 + n];                 // 1 global read, 8 FMA reuse
        #pragma unroll
        for (int p = 0; p < TPTS; p++) acc2[p] = fmaf(tm[p][k], wv, acc2[p]);
    }
    #pragma unroll
    for (int p = 0; p < TPTS; p++)
        g_table[((size_t)l * NT + pt0 + p) * 128 + n] = acc2[p] * Cv[p];
}

// ---------------- weight prep: bf16 transpose of 9 node matrices ------------
__global__ __launch_bounds__(256) void wprep_kernel(
    const float* __restrict__ c1, const float* __restrict__ c2,
    const float* __restrict__ lwp)
{
    int gid = blockIdx.x * 256 + threadIdx.x;       // 576*256 = 147456 exact
    int mat = gid >> 14, r = gid & 16383;
    int n = r & 127, k = r >> 7;
    int l = mat / 3, w = mat % 3;
    const float* base = (w == 0 ? c1 : w == 1 ? c2 : lwp) + (size_t)l * HID * HID;
    g_wT[(size_t)mat * HID * HID + n * 128 + k] = f2bfbits(base[k * 128 + n]);
}

// ---------------- layer-0 conv1: emb gather + h init + GEMM (round-12) -----
__global__ __launch_bounds__(256) void conv1_kernel(
    const int* __restrict__ z, const float* __restrict__ emb)
{
    __shared__ __align__(16) unsigned short a_s[32 * 128];    // 8 KB
    __shared__ int zl[32];
    int tid = threadIdx.x;
    int wave = tid >> 6, lane = tid & 63, quad = lane >> 4, l16 = lane & 15;
    int mtile = (wave & 1) * 16, nbase = (wave >> 1) * 64;
    for (int t = blockIdx.x; t < NTILES; t += gridDim.x){
        int base = t * 32;
        __syncthreads();
        if (tid < 32) zl[tid] = (base + tid < N_NODES) ? z[base + tid] : 0;
        __syncthreads();
        for (int i = tid; i < 512; i += 256){
            int nn = i >> 4, c = i & 15, node = base + nn;
            int phys = c ^ (nn & 15);
            uint4 q = {0u, 0u, 0u, 0u};
            if (node < N_NODES){
                const float* p = &emb[(size_t)zl[nn] * 128 + c * 8];
                float4 f0 = *(const float4*)p;
                float4 f1 = *(const float4*)(p + 4);
                *(float4*)&g_h[(size_t)node * 128 + c * 8]     = f0;
                *(float4*)&g_h[(size_t)node * 128 + c * 8 + 4] = f1;
                q.x = (unsigned int)f2bfbits(f0.x) | ((unsigned int)f2bfbits(f0.y) << 16);
                q.y = (unsigned int)f2bfbits(f0.z) | ((unsigned int)f2bfbits(f0.w) << 16);
                q.z = (unsigned int)f2bfbits(f1.x) | ((unsigned int)f2bfbits(f1.y) << 16);
                q.w = (unsigned int)f2bfbits(f1.z) | ((unsigned int)f2bfbits(f1.w) << 16);
            }
            *(uint4*)&a_s[nn * 128 + phys * 8] = q;
        }
        __syncthreads();
        bf16x8 av[4];
        int arow = mtile + l16;
        #pragma unroll
        for (int ks = 0; ks < 4; ks++){
            int phys = (ks * 4 + quad) ^ (arow & 15);
            av[ks] = *(const bf16x8*)&a_s[arow * 128 + phys * 8];
        }
        f32x4 acc[4] = {};
        #pragma unroll
        for (int nt = 0; nt < 4; nt++){
            int n = nbase + nt * 16 + l16;
            #pragma unroll
            for (int ks = 0; ks < 4; ks++){
                bf16x8 bv = *(const bf16x8*)&g_wT[n * 128 + ks * 32 + quad * 8];
                acc[nt] = __builtin_amdgcn_mfma_f32_16x16x32_bf16(av[ks], bv, acc[nt], 0, 0, 0);
            }
        }
        #pragma unroll
        for (int nt = 0; nt < 4; nt++){
            int n = nbase + nt * 16 + l16;
            #pragma unroll
            for (int r = 0; r < 4; r++){
                int node = base + mtile + quad * 4 + r;
                if (node < N_NODES)
                    g_xfb[(size_t)node * 128 + n] = f2bfbits(acc[nt][r]);
            }
        }
    }
}

// ---------------- wave-autonomous fused GEMM chain (16-node tiles, r12) -----
__global__ __launch_bounds__(256) void fused_kernel(
    int l, const float* __restrict__ bias2, const float* __restrict__ biasl,
    int skip3)
{
    __shared__ __align__(16) unsigned short t_sl[4][16 * 128];  // 16 KB
    int tid = threadIdx.x;
    int wave = tid >> 6, lane = tid & 63, quad = lane >> 4, l16 = lane & 15;
    const unsigned short* c2  = g_wT + (size_t)(l * 3 + 1) * HID * HID;
    const unsigned short* lw  = g_wT + (size_t)(l * 3 + 2) * HID * HID;
    const unsigned short* c1n = g_wT + (size_t)((l + 1) * 3) * HID * HID;
    unsigned short* ts = t_sl[wave];

    int wt = blockIdx.x * 4 + wave;            // 782*4 = 3128 >= NWT
    if (wt >= NWT) return;
    int base = wt * 16;

    float b2r[8], blr[8];
    #pragma unroll
    for (int nt = 0; nt < 8; nt++){
        b2r[nt] = bias2[nt * 16 + l16];
        blr[nt] = biasl[nt * 16 + l16];
    }

    // ---- GEMM1: acc = aggb(tile) @ c2   (A direct from global, B from L2)
    bf16x8 av[4];
    #pragma unroll
    for (int ks = 0; ks < 4; ks++)
        av[ks] = *(const bf16x8*)&g_aggb[(size_t)(base + l16) * 128 + ks * 32 + quad * 8];
    f32x4 acc[8] = {};
    #pragma unroll
    for (int nt = 0; nt < 8; nt++){
        int n = nt * 16 + l16;
        #pragma unroll
        for (int ks = 0; ks < 4; ks++){
            bf16x8 bv = *(const bf16x8*)&c2[n * 128 + ks * 32 + quad * 8];
            acc[nt] = __builtin_amdgcn_mfma_f32_16x16x32_bf16(av[ks], bv, acc[nt], 0, 0, 0);
        }
    }
    // epilogue1: t = ssp(acc + b2) -> ts (swizzled; wave-internal ordering)
    #pragma unroll
    for (int nt = 0; nt < 8; nt++){
        int col = nt * 16 + l16;
        int c = col >> 3, sub = col & 7;
        #pragma unroll
        for (int r = 0; r < 4; r++){
            int row = quad * 4 + r;
            ts[row * 128 + ((c ^ row) & 15) * 8 + sub] =
                f2bfbits(sspf(acc[nt][r] + b2r[nt]));
        }
    }

    // ---- GEMM2: acc2 = t @ lw
    #pragma unroll
    for (int ks = 0; ks < 4; ks++){
        int phys = (ks * 4 + quad) ^ l16;
        av[ks] = *(const bf16x8*)&ts[l16 * 128 + phys * 8];
    }
    f32x4 acc2[8] = {};
    #pragma unroll
    for (int nt = 0; nt < 8; nt++){
        int n = nt * 16 + l16;
        #pragma unroll
        for (int ks = 0; ks < 4; ks++){
            bf16x8 bv = *(const bf16x8*)&lw[n * 128 + ks * 32 + quad * 8];
            acc2[nt] = __builtin_amdgcn_mfma_f32_16x16x32_bf16(av[ks], bv, acc2[nt], 0, 0, 0);
        }
    }
    // epilogue2: h += acc2 + lb; stash bf16(h) into ts for GEMM3
    #pragma unroll
    for (int nt = 0; nt < 8; nt++){
        int col = nt * 16 + l16;
        int c = col >> 3, sub = col & 7;
        #pragma unroll
        for (int r = 0; r < 4; r++){
            int row = quad * 4 + r;
            size_t o = (size_t)(base + row) * 128 + col;
            float hv = g_h[o] + acc2[nt][r] + blr[nt];
            g_h[o] = hv;
            if (!skip3)
                ts[row * 128 + ((c ^ row) & 15) * 8 + sub] = f2bfbits(hv);
        }
    }
    if (skip3) return;

    // ---- GEMM3: xfb = bf16(h) @ c1next
    #pragma unroll
    for (int ks = 0; ks < 4; ks++){
        int phys = (ks * 4 + quad) ^ l16;
        av[ks] = *(const bf16x8*)&ts[l16 * 128 + phys * 8];
    }
    f32x4 acc3[8] = {};
    #pragma unroll
    for (int nt = 0; nt < 8; nt++){
        int n = nt * 16 + l16;
        #pragma unroll
        for (int ks = 0; ks < 4; ks++){
            bf16x8 bv = *(const bf16x8*)&c1n[n * 128 + ks * 32 + quad * 8];
            acc3[nt] = __builtin_amdgcn_mfma_f32_16x16x32_bf16(av[ks], bv, acc3[nt], 0, 0, 0);
        }
    }
    #pragma unroll
    for (int nt = 0; nt < 8; nt++){
        int col = nt * 16 + l16;
        #pragma unroll
        for (int r = 0; r < 4; r++){
            int row = quad * 4 + r;
            g_xfb[(size_t)(base + row) * 128 + col] = f2bfbits(acc3[nt][r]);
        }
    }
}

// ---------------- CSR edge aggregation: nearest-table, 4-edge unroll --------
__global__ __launch_bounds__(256) void agg_kernel(int l){
    const float* __restrict__ T = g_table + (size_t)l * NT * 128;
    int tid = threadIdx.x;
    int grp = tid >> 5, n0 = (tid & 31) * 4;
    int v = blockIdx.x * 8 + grp;                   // 6250 blocks * 8 = 50000 exact
    int e1 = g_row[v];
    int e0 = e1 - g_cnt[v];
    float a0 = 0.f, a1 = 0.f, a2 = 0.f, a3 = 0.f;
    int j = e0;
    for (; j + 4 <= e1; j += 4){
        int sA = g_ssrc[j],   sB = g_ssrc[j+1];
        int sC = g_ssrc[j+2], sD = g_ssrc[j+3];
        int iA = g_sidx[j],   iB = g_sidx[j+1];
        int iC = g_sidx[j+2], iD = g_sidx[j+3];
        float4 tA = *(const float4*)&T[(size_t)iA * 128 + n0];
        float4 tB = *(const float4*)&T[(size_t)iB * 128 + n0];
        float4 tC = *(const float4*)&T[(size_t)iC * 128 + n0];
        float4 tD = *(const float4*)&T[(size_t)iD * 128 + n0];
        ushort4 gA = *(const ushort4*)&g_xfb[(size_t)sA * 128 + n0];
        ushort4 gB = *(const ushort4*)&g_xfb[(size_t)sB * 128 + n0];
        ushort4 gC = *(const ushort4*)&g_xfb[(size_t)sC * 128 + n0];
        ushort4 gD = *(const ushort4*)&g_xfb[(size_t)sD * 128 + n0];
        a0 = fmaf(tA.x, bf2f(gA.x), a0); a1 = fmaf(tA.y, bf2f(gA.y), a1);
        a2 = fmaf(tA.z, bf2f(gA.z), a2); a3 = fmaf(tA.w, bf2f(gA.w), a3);
        a0 = fmaf(tB.x, bf2f(gB.x), a0); a1 = fmaf(tB.y, bf2f(gB.y), a1);
        a2 = fmaf(tB.z, bf2f(gB.z), a2); a3 = fmaf(tB.w, bf2f(gB.w), a3);
        a0 = fmaf(tC.x, bf2f(gC.x), a0); a1 = fmaf(tC.y, bf2f(gC.y), a1);
        a2 = fmaf(tC.z, bf2f(gC.z), a2); a3 = fmaf(tC.w, bf2f(gC.w), a3);
        a0 = fmaf(tD.x, bf2f(gD.x), a0); a1 = fmaf(tD.y, bf2f(gD.y), a1);
        a2 = fmaf(tD.z, bf2f(gD.z), a2); a3 = fmaf(tD.w, bf2f(gD.w), a3);
    }
    for (; j < e1; j++){
        int s = g_ssrc[j], i0 = g_sidx[j];
        float4 t0 = *(const float4*)&T[(size_t)i0 * 128 + n0];
        ushort4 g = *(const ushort4*)&g_xfb[(size_t)s * 128 + n0];
        a0 = fmaf(t0.x, bf2f(g.x), a0); a1 = fmaf(t0.y, bf2f(g.y), a1);
        a2 = fmaf(t0.z, bf2f(g.z), a2); a3 = fmaf(t0.w, bf2f(g.w), a3);
    }
    ushort4 o;
    o.x = f2bfbits(a0); o.y = f2bfbits(a1); o.z = f2bfbits(a2); o.w = f2bfbits(a3);
    *(ushort4*)&g_aggb[(size_t)v * 128 + n0] = o;
}

// ---------------- output head + fused graph segment-sum ---------------------
__global__ __launch_bounds__(256) void head_kernel(
    const float* __restrict__ w1g, const float* __restrict__ b1g,
    const float* __restrict__ w2g, const float* __restrict__ b2g,
    const int* __restrict__ batch)
{
    __shared__ __align__(16) float w1h[128 * 64];   // 32 KB
    __shared__ __align__(16) float w2h[64];
    __shared__ __align__(16) float b1h[64];
    __shared__ __align__(16) float hrow[4][128];
    __shared__ float part[NGRAPHS];
    int tid = threadIdx.x;
    for (int i = tid; i < 128 * 64 / 4; i += 256)
        *(float4*)&w1h[i * 4] = *(const float4*)&w1g[i * 4];
    if (tid < 64){ w2h[tid] = w2g[tid]; b1h[tid] = b1g[tid]; }
    if (tid < NGRAPHS) part[tid] = 0.0f;
    float sb2 = b2g[0];
    __syncthreads();
    int wave = tid >> 6, lane = tid & 63;
    for (int nb = blockIdx.x * 4; nb < N_NODES; nb += gridDim.x * 4){
        int node = nb + wave;
        __syncthreads();
        if (node < N_NODES){
            hrow[wave][lane]      = g_h[(size_t)node * 128 + lane];
            hrow[wave][64 + lane] = g_h[(size_t)node * 128 + 64 + lane];
        }
        __syncthreads();
        if (node < N_NODES){
            float acc = b1h[lane];
            #pragma unroll 8
            for (int k = 0; k < 128; k++)
                acc = fmaf(hrow[wave][k], w1h[k * 64 + lane], acc);
            acc = sspf(acc) * w2h[lane];
            #pragma unroll
            for (int off = 32; off > 0; off >>= 1) acc += __shfl_down(acc, off, 64);
            if (lane == 0) atomicAdd(&part[batch[node]], acc + sb2);
        }
    }
    __syncthreads();
    if (tid < NGRAPHS && part[tid] != 0.0f)
        __hip_atomic_fetch_add(&g_gout[tid], part[tid],
                               __ATOMIC_RELAXED, __HIP_MEMORY_SCOPE_AGENT);
}

__global__ void store_kernel(float* __restrict__ out){
    int i = threadIdx.x;
    if (i < NGRAPHS) out[i] = g_gout[i];
}

extern "C" void kernel_launch(void* const* d_in, const int* in_sizes, int n_in,
                              void* d_out, int out_size, void* d_ws, size_t ws_size,
                              hipStream_t stream)
{
    const int* z       = (const int*)d_in[0];
    const float* pos   = (const float*)d_in[1];
    const int* ei      = (const int*)d_in[2];
    const int* src = ei;
    const int* dst = ei + N_EDGES;
    const int* batch   = (const int*)d_in[3];
    const float* emb     = (const float*)d_in[4];
    const float* mlp_w1  = (const float*)d_in[5];
    const float* mlp_b1  = (const float*)d_in[6];
    const float* mlp_w2  = (const float*)d_in[7];
    const float* mlp_b2  = (const float*)d_in[8];
    const float* conv1_w = (const float*)d_in[9];
    const float* conv2_w = (const float*)d_in[10];
    const float* conv2_b = (const float*)d_in[11];
    const float* lin_w   = (const float*)d_in[12];
    const float* lin_b   = (const float*)d_in[13];
    const float* out1_w  = (const float*)d_in[14];
    const float* out1_b  = (const float*)d_in[15];
    const float* out2_w  = (const float*)d_in[16];
    const float* out2_b  = (const float*)d_in[17];
    (void)d_ws; (void)ws_size; (void)in_sizes; (void)n_in; (void)out_size;

    // --- one-time: CSR sort, tables, weight prep ---
    zero_cnt_kernel<<<196, 256, 0, stream>>>();
    hist_kernel<<<2500, 256, 0, stream>>>(dst);
    scan1_kernel<<<196, 256, 0, stream>>>();
    scan2_kernel<<<1, 256, 0, stream>>>();
    scan3_kernel<<<196, 256, 0, stream>>>();
    scatter_kernel<<<2500, 256, 0, stream>>>(pos, src, dst);
    table_kernel<<<NL * (NT / TPTS), 128, 0, stream>>>(mlp_w1, mlp_b1, mlp_w2, mlp_b2);
    wprep_kernel<<<576, 256, 0, stream>>>(conv1_w, conv2_w, lin_w);

    conv1_kernel<<<NTILES, 256, 0, stream>>>(z, emb);  // h init + layer-0 conv1
    for (int l = 0; l < NL; l++){
        agg_kernel<<<6250, 256, 0, stream>>>(l);
        fused_kernel<<<(NWT + 3) / 4, 256, 0, stream>>>(l, conv2_b + (size_t)l * HID,
                                                        lin_b + (size_t)l * HID, l == NL - 1);
    }

    head_kernel<<<512, 256, 0, stream>>>(out1_w, out1_b, out2_w, out2_b, batch);
    store_kernel<<<1, 64, 0, stream>>>((float*)d_out);
}

// Round 15
// 555.693 us; speedup vs baseline: 1.3487x; 1.0820x over previous
//
#include <hip/hip_runtime.h>
#include <math.h>

#define N_NODES 50000
#define N_EDGES 640000
#define HID 128
#define NL 3
#define NGRAPHS 64
#define NT 4096
#define TPTS 8
#define DMAX 1.7330f
#define NPAD 50176   // 196*256
#define NTILES 1563  // ceil(50000/32)
#define NWT 3125     // 50000/16 wave-tiles

typedef __attribute__((ext_vector_type(8))) short bf16x8;
typedef __attribute__((ext_vector_type(4))) float f32x4;

// ---------------- module-scope device buffers -------------------------------
__device__ __align__(16) float g_h  [N_NODES * HID];           // f32 node features
__device__ __align__(16) unsigned short g_xfb [N_NODES * HID]; // bf16 xf
__device__ __align__(16) unsigned short g_aggb[N_NODES * HID]; // bf16 aggregation
__device__ __align__(16) float g_table[NL * NT * HID];         // W(d)*C(d), 6 MB
__device__ __align__(16) unsigned short g_wT[9 * HID * HID];   // bf16 [n][k]
__device__ __align__(16) unsigned short g_w1hT[64 * HID];      // bf16 out1_w [n][k]
__device__ __align__(16) int   g_cnt[NPAD];
__device__ __align__(16) int   g_ex [NPAD];
__device__ __align__(16) int   g_row[NPAD];
__device__ __align__(16) int   g_part[256];
__device__ __align__(16) int   g_ssrc[N_EDGES];
__device__ __align__(16) int   g_sidx[N_EDGES];                // nearest table idx
__device__ __align__(16) float g_gout[NGRAPHS];

__device__ __forceinline__ unsigned short f2bfbits(float x){
    union { float f; unsigned int i; } v; v.f = x;
    unsigned int lsb = (v.i >> 16) & 1;
    v.i += 0x7fff + lsb;                      // RNE to bf16
    return (unsigned short)(v.i >> 16);
}
__device__ __forceinline__ float bf2f(unsigned short u){
    union { unsigned int i; float f; } v; v.i = ((unsigned int)u) << 16; return v.f;
}
__device__ __forceinline__ float sspf(float x){
    return fmaxf(x, 0.0f) + log1pf(__expf(-fabsf(x))) - 0.69314718055994530942f;
}

// ---------------- counting sort of edges by dst ------------------------------
__global__ __launch_bounds__(256) void zero_cnt_kernel(){
    int i = blockIdx.x * 256 + threadIdx.x;
    g_cnt[i] = 0;                                   // NPAD exact
    if (blockIdx.x == 0 && threadIdx.x < NGRAPHS) g_gout[threadIdx.x] = 0.0f;
}
__global__ __launch_bounds__(256) void hist_kernel(const int* __restrict__ dst){
    int e = blockIdx.x * 256 + threadIdx.x;         // 2500*256 exact
    atomicAdd(&g_cnt[dst[e]], 1);
}
__global__ __launch_bounds__(256) void scan1_kernel(){
    __shared__ int s[256];
    int b = blockIdx.x, t = threadIdx.x, i = b * 256 + t;
    int c = g_cnt[i];
    s[t] = c; __syncthreads();
    #pragma unroll
    for (int off = 1; off < 256; off <<= 1){
        int v = (t >= off) ? s[t - off] : 0; __syncthreads();
        s[t] += v; __syncthreads();
    }
    g_ex[i] = s[t] - c;
    if (t == 255) g_part[b] = s[255];
}
__global__ __launch_bounds__(256) void scan2_kernel(){
    __shared__ int s[256];
    int t = threadIdx.x;
    s[t] = (t < 196) ? g_part[t] : 0; __syncthreads();
    #pragma unroll
    for (int off = 1; off < 256; off <<= 1){
        int v = (t >= off) ? s[t - off] : 0; __syncthreads();
        s[t] += v; __syncthreads();
    }
    g_part[t] = s[t];
}
__global__ __launch_bounds__(256) void scan3_kernel(){
    int b = blockIdx.x, i = b * 256 + threadIdx.x;
    g_row[i] = g_ex[i] + (b > 0 ? g_part[b - 1] : 0);
}
__global__ __launch_bounds__(256) void scatter_kernel(
    const float* __restrict__ pos, const int* __restrict__ src,
    const int* __restrict__ dst)
{
    int e = blockIdx.x * 256 + threadIdx.x;         // exact
    int sv = src[e], dv = dst[e];
    float dx = pos[3*dv]   - pos[3*sv];
    float dy = pos[3*dv+1] - pos[3*sv+1];
    float dz = pos[3*dv+2] - pos[3*sv+2];
    float d = sqrtf(dx*dx + dy*dy + dz*dz);         // < sqrt(3) < DMAX
    int p = atomicAdd(&g_row[dv], 1);               // g_row[v] ends at end-offset
    g_ssrc[p] = sv;
    g_sidx[p] = (int)(d * ((float)(NT - 1) / DMAX) + 0.5f);  // nearest
}

// ---------------- per-layer filter table: 8 points/block, w2 row-reuse ------
__global__ __launch_bounds__(128) void table_kernel(
    const float* __restrict__ w1g, const float* __restrict__ b1g,
    const float* __restrict__ w2g, const float* __restrict__ b2g)
{
    int bid = blockIdx.x;                           // 3 * NT/TPTS blocks
    int l = bid / (NT / TPTS);
    int pt0 = (bid % (NT / TPTS)) * TPTS;
    int n = threadIdx.x;
    __shared__ __align__(16) float w1s[50 * 128];   // 25.6 KB
    __shared__ float ea[TPTS][50];
    __shared__ float tm[TPTS][128];
    __shared__ float Cv[TPTS];
    for (int i = n; i < 50 * 128; i += 128) w1s[i] = w1g[(size_t)l * 50 * 128 + i];
    if (n < 50){
        const float step = 5.0f / 49.0f;
        #pragma unroll
        for (int p = 0; p < TPTS; p++){
            float d = (pt0 + p) * (DMAX / (float)(NT - 1));
            float srel = d * 0.2f;
            float env = expf(1.0f - 1.0f / (1.0f - srel * srel));
            float dd = d - step * (float)n;
            ea[p][n] = expf((-0.5f / (step * step)) * dd * dd) * env;
        }
    }
    if (n < TPTS){
        float d = (pt0 + n) * (DMAX / (float)(NT - 1));
        Cv[n] = 0.5f * (cosf(d * 0.62831853071795864769f) + 1.0f);
    }
    __syncthreads();
    float b1v = b1g[l * 128 + n];
    #pragma unroll
    for (int p = 0; p < TPTS; p++){
        float acc = b1v;
        #pragma unroll 10
        for (int k = 0; k < 50; k++) acc = fmaf(ea[p][k], w1s[k * 128 + n], acc);
        tm[p][n] = sspf(acc);
    }
    __syncthreads();
    float b2v = b2g[l * 128 + n];
    float acc2[TPTS];
    #pragma unroll
    for (int p = 0; p < TPTS; p++) acc2[p] = b2v;
    const float* w2 = w2g + (size_t)l * 128 * 128;
    for (int k = 0; k < 128; k++){
        float wv = w2[k * 128 + n];                 // 1 global read, 8 FMA reuse
        #pragma unroll
        for (int p = 0; p < TPTS; p++) acc2[p] = fmaf(tm[p][k], wv, acc2[p]);
    }
    #pragma unroll
    for (int p = 0; p < TPTS; p++)
        g_table[((size_t)l * NT + pt0 + p) * 128 + n] = acc2[p] * Cv[p];
}

// ---------------- weight prep: bf16 transpose of 9 node matrices ------------
__global__ __launch_bounds__(256) void wprep_kernel(
    const float* __restrict__ c1, const float* __restrict__ c2,
    const float* __restrict__ lwp)
{
    int gid = blockIdx.x * 256 + threadIdx.x;       // 576*256 = 147456 exact
    int mat = gid >> 14, r = gid & 16383;
    int n = r & 127, k = r >> 7;
    int l = mat / 3, w = mat % 3;
    const float* base = (w == 0 ? c1 : w == 1 ? c2 : lwp) + (size_t)l * HID * HID;
    g_wT[(size_t)mat * HID * HID + n * 128 + k] = f2bfbits(base[k * 128 + n]);
}

// out1_w [128][64] -> bf16 [n=64][k=128]
__global__ __launch_bounds__(256) void wprep2_kernel(const float* __restrict__ w1g){
    int gid = blockIdx.x * 256 + threadIdx.x;       // 32*256 = 8192 exact
    int n = gid & 63, k = gid >> 6;
    g_w1hT[n * 128 + k] = f2bfbits(w1g[k * 64 + n]);
}

// ---------------- layer-0 conv1: emb gather + h init + GEMM -----------------
__global__ __launch_bounds__(256) void conv1_kernel(
    const int* __restrict__ z, const float* __restrict__ emb)
{
    __shared__ __align__(16) unsigned short a_s[32 * 128];    // 8 KB
    __shared__ int zl[32];
    int tid = threadIdx.x;
    int wave = tid >> 6, lane = tid & 63, quad = lane >> 4, l16 = lane & 15;
    int mtile = (wave & 1) * 16, nbase = (wave >> 1) * 64;
    for (int t = blockIdx.x; t < NTILES; t += gridDim.x){
        int base = t * 32;
        __syncthreads();
        if (tid < 32) zl[tid] = (base + tid < N_NODES) ? z[base + tid] : 0;
        __syncthreads();
        for (int i = tid; i < 512; i += 256){
            int nn = i >> 4, c = i & 15, node = base + nn;
            int phys = c ^ (nn & 15);
            uint4 q = {0u, 0u, 0u, 0u};
            if (node < N_NODES){
                const float* p = &emb[(size_t)zl[nn] * 128 + c * 8];
                float4 f0 = *(const float4*)p;
                float4 f1 = *(const float4*)(p + 4);
                *(float4*)&g_h[(size_t)node * 128 + c * 8]     = f0;
                *(float4*)&g_h[(size_t)node * 128 + c * 8 + 4] = f1;
                q.x = (unsigned int)f2bfbits(f0.x) | ((unsigned int)f2bfbits(f0.y) << 16);
                q.y = (unsigned int)f2bfbits(f0.z) | ((unsigned int)f2bfbits(f0.w) << 16);
                q.z = (unsigned int)f2bfbits(f1.x) | ((unsigned int)f2bfbits(f1.y) << 16);
                q.w = (unsigned int)f2bfbits(f1.z) | ((unsigned int)f2bfbits(f1.w) << 16);
            }
            *(uint4*)&a_s[nn * 128 + phys * 8] = q;
        }
        __syncthreads();
        bf16x8 av[4];
        int arow = mtile + l16;
        #pragma unroll
        for (int ks = 0; ks < 4; ks++){
            int phys = (ks * 4 + quad) ^ (arow & 15);
            av[ks] = *(const bf16x8*)&a_s[arow * 128 + phys * 8];
        }
        f32x4 acc[4] = {};
        #pragma unroll
        for (int nt = 0; nt < 4; nt++){
            int n = nbase + nt * 16 + l16;
            #pragma unroll
            for (int ks = 0; ks < 4; ks++){
                bf16x8 bv = *(const bf16x8*)&g_wT[n * 128 + ks * 32 + quad * 8];
                acc[nt] = __builtin_amdgcn_mfma_f32_16x16x32_bf16(av[ks], bv, acc[nt], 0, 0, 0);
            }
        }
        #pragma unroll
        for (int nt = 0; nt < 4; nt++){
            int n = nbase + nt * 16 + l16;
            #pragma unroll
            for (int r = 0; r < 4; r++){
                int node = base + mtile + quad * 4 + r;
                if (node < N_NODES)
                    g_xfb[(size_t)node * 128 + n] = f2bfbits(acc[nt][r]);
            }
        }
    }
}

// ---------------- wave-autonomous fused GEMM chain (16-node tiles) ----------
__global__ __launch_bounds__(256) void fused_kernel(
    int l, const float* __restrict__ bias2, const float* __restrict__ biasl,
    int skip3)
{
    __shared__ __align__(16) unsigned short t_sl[4][16 * 128];  // 16 KB
    int tid = threadIdx.x;
    int wave = tid >> 6, lane = tid & 63, quad = lane >> 4, l16 = lane & 15;
    const unsigned short* c2  = g_wT + (size_t)(l * 3 + 1) * HID * HID;
    const unsigned short* lw  = g_wT + (size_t)(l * 3 + 2) * HID * HID;
    const unsigned short* c1n = g_wT + (size_t)((l + 1) * 3) * HID * HID;
    unsigned short* ts = t_sl[wave];

    int wt = blockIdx.x * 4 + wave;            // 782*4 = 3128 >= NWT
    if (wt >= NWT) return;
    int base = wt * 16;

    float b2r[8], blr[8];
    #pragma unroll
    for (int nt = 0; nt < 8; nt++){
        b2r[nt] = bias2[nt * 16 + l16];
        blr[nt] = biasl[nt * 16 + l16];
    }

    // ---- GEMM1: acc = aggb(tile) @ c2   (A direct from global, B from L2)
    bf16x8 av[4];
    #pragma unroll
    for (int ks = 0; ks < 4; ks++)
        av[ks] = *(const bf16x8*)&g_aggb[(size_t)(base + l16) * 128 + ks * 32 + quad * 8];
    f32x4 acc[8] = {};
    #pragma unroll
    for (int nt = 0; nt < 8; nt++){
        int n = nt * 16 + l16;
        #pragma unroll
        for (int ks = 0; ks < 4; ks++){
            bf16x8 bv = *(const bf16x8*)&c2[n * 128 + ks * 32 + quad * 8];
            acc[nt] = __builtin_amdgcn_mfma_f32_16x16x32_bf16(av[ks], bv, acc[nt], 0, 0, 0);
        }
    }
    // epilogue1: t = ssp(acc + b2) -> ts (swizzled; wave-internal ordering)
    #pragma unroll
    for (int nt = 0; nt < 8; nt++){
        int col = nt * 16 + l16;
        int c = col >> 3, sub = col & 7;
        #pragma unroll
        for (int r = 0; r < 4; r++){
            int row = quad * 4 + r;
            ts[row * 128 + ((c ^ row) & 15) * 8 + sub] =
                f2bfbits(sspf(acc[nt][r] + b2r[nt]));
        }
    }

    // ---- GEMM2: acc2 = t @ lw
    #pragma unroll
    for (int ks = 0; ks < 4; ks++){
        int phys = (ks * 4 + quad) ^ l16;
        av[ks] = *(const bf16x8*)&ts[l16 * 128 + phys * 8];
    }
    f32x4 acc2[8] = {};
    #pragma unroll
    for (int nt = 0; nt < 8; nt++){
        int n = nt * 16 + l16;
        #pragma unroll
        for (int ks = 0; ks < 4; ks++){
            bf16x8 bv = *(const bf16x8*)&lw[n * 128 + ks * 32 + quad * 8];
            acc2[nt] = __builtin_amdgcn_mfma_f32_16x16x32_bf16(av[ks], bv, acc2[nt], 0, 0, 0);
        }
    }
    // epilogue2: h += acc2 + lb; stash bf16(h) into ts for GEMM3
    #pragma unroll
    for (int nt = 0; nt < 8; nt++){
        int col = nt * 16 + l16;
        int c = col >> 3, sub = col & 7;
        #pragma unroll
        for (int r = 0; r < 4; r++){
            int row = quad * 4 + r;
            size_t o = (size_t)(base + row) * 128 + col;
            float hv = g_h[o] + acc2[nt][r] + blr[nt];
            g_h[o] = hv;
            if (!skip3)
                ts[row * 128 + ((c ^ row) & 15) * 8 + sub] = f2bfbits(hv);
        }
    }
    if (skip3) return;

    // ---- GEMM3: xfb = bf16(h) @ c1next
    #pragma unroll
    for (int ks = 0; ks < 4; ks++){
        int phys = (ks * 4 + quad) ^ l16;
        av[ks] = *(const bf16x8*)&ts[l16 * 128 + phys * 8];
    }
    f32x4 acc3[8] = {};
    #pragma unroll
    for (int nt = 0; nt < 8; nt++){
        int n = nt * 16 + l16;
        #pragma unroll
        for (int ks = 0; ks < 4; ks++){
            bf16x8 bv = *(const bf16x8*)&c1n[n * 128 + ks * 32 + quad * 8];
            acc3[nt] = __builtin_amdgcn_mfma_f32_16x16x32_bf16(av[ks], bv, acc3[nt], 0, 0, 0);
        }
    }
    #pragma unroll
    for (int nt = 0; nt < 8; nt++){
        int col = nt * 16 + l16;
        #pragma unroll
        for (int r = 0; r < 4; r++){
            int row = quad * 4 + r;
            g_xfb[(size_t)(base + row) * 128 + col] = f2bfbits(acc3[nt][r]);
        }
    }
}

// ---------------- CSR edge aggregation: nearest-table, 4-edge unroll --------
__global__ __launch_bounds__(256) void agg_kernel(int l){
    const float* __restrict__ T = g_table + (size_t)l * NT * 128;
    int tid = threadIdx.x;
    int grp = tid >> 5, n0 = (tid & 31) * 4;
    int v = blockIdx.x * 8 + grp;                   // 6250 blocks * 8 = 50000 exact
    int e1 = g_row[v];
    int e0 = e1 - g_cnt[v];
    float a0 = 0.f, a1 = 0.f, a2 = 0.f, a3 = 0.f;
    int j = e0;
    for (; j + 4 <= e1; j += 4){
        int sA = g_ssrc[j],   sB = g_ssrc[j+1];
        int sC = g_ssrc[j+2], sD = g_ssrc[j+3];
        int iA = g_sidx[j],   iB = g_sidx[j+1];
        int iC = g_sidx[j+2], iD = g_sidx[j+3];
        float4 tA = *(const float4*)&T[(size_t)iA * 128 + n0];
        float4 tB = *(const float4*)&T[(size_t)iB * 128 + n0];
        float4 tC = *(const float4*)&T[(size_t)iC * 128 + n0];
        float4 tD = *(const float4*)&T[(size_t)iD * 128 + n0];
        ushort4 gA = *(const ushort4*)&g_xfb[(size_t)sA * 128 + n0];
        ushort4 gB = *(const ushort4*)&g_xfb[(size_t)sB * 128 + n0];
        ushort4 gC = *(const ushort4*)&g_xfb[(size_t)sC * 128 + n0];
        ushort4 gD = *(const ushort4*)&g_xfb[(size_t)sD * 128 + n0];
        a0 = fmaf(tA.x, bf2f(gA.x), a0); a1 = fmaf(tA.y, bf2f(gA.y), a1);
        a2 = fmaf(tA.z, bf2f(gA.z), a2); a3 = fmaf(tA.w, bf2f(gA.w), a3);
        a0 = fmaf(tB.x, bf2f(gB.x), a0); a1 = fmaf(tB.y, bf2f(gB.y), a1);
        a2 = fmaf(tB.z, bf2f(gB.z), a2); a3 = fmaf(tB.w, bf2f(gB.w), a3);
        a0 = fmaf(tC.x, bf2f(gC.x), a0); a1 = fmaf(tC.y, bf2f(gC.y), a1);
        a2 = fmaf(tC.z, bf2f(gC.z), a2); a3 = fmaf(tC.w, bf2f(gC.w), a3);
        a0 = fmaf(tD.x, bf2f(gD.x), a0); a1 = fmaf(tD.y, bf2f(gD.y), a1);
        a2 = fmaf(tD.z, bf2f(gD.z), a2); a3 = fmaf(tD.w, bf2f(gD.w), a3);
    }
    for (; j < e1; j++){
        int s = g_ssrc[j], i0 = g_sidx[j];
        float4 t0 = *(const float4*)&T[(size_t)i0 * 128 + n0];
        ushort4 g = *(const ushort4*)&g_xfb[(size_t)s * 128 + n0];
        a0 = fmaf(t0.x, bf2f(g.x), a0); a1 = fmaf(t0.y, bf2f(g.y), a1);
        a2 = fmaf(t0.z, bf2f(g.z), a2); a3 = fmaf(t0.w, bf2f(g.w), a3);
    }
    ushort4 o;
    o.x = f2bfbits(a0); o.y = f2bfbits(a1); o.z = f2bfbits(a2); o.w = f2bfbits(a3);
    *(ushort4*)&g_aggb[(size_t)v * 128 + n0] = o;
}

// ---------------- output head: MFMA GEMM + quad-butterfly + seg-sum ---------
__global__ __launch_bounds__(256) void head_kernel(
    const float* __restrict__ b1g, const float* __restrict__ w2g,
    const float* __restrict__ b2g, const int* __restrict__ batch)
{
    __shared__ float part[NGRAPHS];
    int tid = threadIdx.x;
    int wave = tid >> 6, lane = tid & 63, quad = lane >> 4, l16 = lane & 15;
    if (tid < NGRAPHS) part[tid] = 0.0f;
    __syncthreads();
    float sb2 = b2g[0];

    int wt = blockIdx.x * 4 + wave;            // 782 blocks; 50000 = 3125*16 exact
    if (wt < NWT){
        int base = wt * 16;
        float b1r[4], w2r[4];
        #pragma unroll
        for (int nt = 0; nt < 4; nt++){
            b1r[nt] = b1g[nt * 16 + l16];
            w2r[nt] = w2g[nt * 16 + l16];
        }
        // A-fragments from g_h (f32 -> bf16 pack), row = base + l16
        bf16x8 av[4];
        #pragma unroll
        for (int ks = 0; ks < 4; ks++){
            const float* p = &g_h[(size_t)(base + l16) * 128 + ks * 32 + quad * 8];
            float4 f0 = *(const float4*)p;
            float4 f1 = *(const float4*)(p + 4);
            union { unsigned int u[4]; bf16x8 v; } pk;
            pk.u[0] = (unsigned int)f2bfbits(f0.x) | ((unsigned int)f2bfbits(f0.y) << 16);
            pk.u[1] = (unsigned int)f2bfbits(f0.z) | ((unsigned int)f2bfbits(f0.w) << 16);
            pk.u[2] = (unsigned int)f2bfbits(f1.x) | ((unsigned int)f2bfbits(f1.y) << 16);
            pk.u[3] = (unsigned int)f2bfbits(f1.z) | ((unsigned int)f2bfbits(f1.w) << 16);
            av[ks] = pk.v;
        }
        f32x4 acc[4] = {};
        #pragma unroll
        for (int nt = 0; nt < 4; nt++){
            int n = nt * 16 + l16;
            #pragma unroll
            for (int ks = 0; ks < 4; ks++){
                bf16x8 bv = *(const bf16x8*)&g_w1hT[n * 128 + ks * 32 + quad * 8];
                acc[nt] = __builtin_amdgcn_mfma_f32_16x16x32_bf16(av[ks], bv, acc[nt], 0, 0, 0);
            }
        }
        // e-row partial: srow[r] = sum_nt ssp(acc+b1)*w2, then 16-lane butterfly
        float srow[4];
        #pragma unroll
        for (int r = 0; r < 4; r++){
            float s = 0.0f;
            #pragma unroll
            for (int nt = 0; nt < 4; nt++)
                s += sspf(acc[nt][r] + b1r[nt]) * w2r[nt];
            #pragma unroll
            for (int off = 1; off < 16; off <<= 1)
                s += __shfl_xor(s, off, 64);
            srow[r] = s;
        }
        if (l16 == 0){
            #pragma unroll
            for (int r = 0; r < 4; r++){
                int node = base + quad * 4 + r;
                atomicAdd(&part[batch[node]], srow[r] + sb2);
            }
        }
    }
    __syncthreads();
    if (tid < NGRAPHS && part[tid] != 0.0f)
        __hip_atomic_fetch_add(&g_gout[tid], part[tid],
                               __ATOMIC_RELAXED, __HIP_MEMORY_SCOPE_AGENT);
}

__global__ void store_kernel(float* __restrict__ out){
    int i = threadIdx.x;
    if (i < NGRAPHS) out[i] = g_gout[i];
}

extern "C" void kernel_launch(void* const* d_in, const int* in_sizes, int n_in,
                              void* d_out, int out_size, void* d_ws, size_t ws_size,
                              hipStream_t stream)
{
    const int* z       = (const int*)d_in[0];
    const float* pos   = (const float*)d_in[1];
    const int* ei      = (const int*)d_in[2];
    const int* src = ei;
    const int* dst = ei + N_EDGES;
    const int* batch   = (const int*)d_in[3];
    const float* emb     = (const float*)d_in[4];
    const float* mlp_w1  = (const float*)d_in[5];
    const float* mlp_b1  = (const float*)d_in[6];
    const float* mlp_w2  = (const float*)d_in[7];
    const float* mlp_b2  = (const float*)d_in[8];
    const float* conv1_w = (const float*)d_in[9];
    const float* conv2_w = (const float*)d_in[10];
    const float* conv2_b = (const float*)d_in[11];
    const float* lin_w   = (const float*)d_in[12];
    const float* lin_b   = (const float*)d_in[13];
    const float* out1_w  = (const float*)d_in[14];
    const float* out1_b  = (const float*)d_in[15];
    const float* out2_w  = (const float*)d_in[16];
    const float* out2_b  = (const float*)d_in[17];
    (void)d_ws; (void)ws_size; (void)in_sizes; (void)n_in; (void)out_size;

    // --- one-time: CSR sort, tables, weight prep ---
    zero_cnt_kernel<<<196, 256, 0, stream>>>();
    hist_kernel<<<2500, 256, 0, stream>>>(dst);
    scan1_kernel<<<196, 256, 0, stream>>>();
    scan2_kernel<<<1, 256, 0, stream>>>();
    scan3_kernel<<<196, 256, 0, stream>>>();
    scatter_kernel<<<2500, 256, 0, stream>>>(pos, src, dst);
    table_kernel<<<NL * (NT / TPTS), 128, 0, stream>>>(mlp_w1, mlp_b1, mlp_w2, mlp_b2);
    wprep_kernel<<<576, 256, 0, stream>>>(conv1_w, conv2_w, lin_w);
    wprep2_kernel<<<32, 256, 0, stream>>>(out1_w);

    conv1_kernel<<<NTILES, 256, 0, stream>>>(z, emb);  // h init + layer-0 conv1
    for (int l = 0; l < NL; l++){
        agg_kernel<<<6250, 256, 0, stream>>>(l);
        fused_kernel<<<(NWT + 3) / 4, 256, 0, stream>>>(l, conv2_b + (size_t)l * HID,
                                                        lin_b + (size_t)l * HID, l == NL - 1);
    }

    head_kernel<<<(NWT + 3) / 4, 256, 0, stream>>>(out1_b, out2_w, out2_b, batch);
    store_kernel<<<1, 64, 0, stream>>>((float*)d_out);
}

// Round 16
// 509.788 us; speedup vs baseline: 1.4701x; 1.0900x over previous
//
#include <hip/hip_runtime.h>
#include <math.h>

#define N_NODES 50000
#define N_EDGES 640000
#define HID 128
#define NL 3
#define NGRAPHS 64
#define NT 4096
#define TPTS 8
#define DMAX 1.7330f
#define NPAD 50176   // 196*256
#define NTILES 1563  // ceil(50000/32)
#define NWT 3125     // 50000/16 wave-tiles

typedef __attribute__((ext_vector_type(8))) short bf16x8;
typedef __attribute__((ext_vector_type(4))) float f32x4;

// ---------------- module-scope device buffers -------------------------------
__device__ __align__(16) float g_h  [N_NODES * HID];           // f32 node features
__device__ __align__(16) unsigned short g_xfb [N_NODES * HID]; // bf16 xf
__device__ __align__(16) unsigned short g_aggb[N_NODES * HID]; // bf16 aggregation
__device__ __align__(16) unsigned short g_table[NL * NT * HID];// bf16 W(d)*C(d), 3 MB
__device__ __align__(16) unsigned short g_wT[9 * HID * HID];   // bf16 [n][k]
__device__ __align__(16) unsigned short g_w1hT[64 * HID];      // bf16 out1_w [n][k]
__device__ __align__(16) int   g_cnt[NPAD];
__device__ __align__(16) int   g_ex [NPAD];
__device__ __align__(16) int   g_row[NPAD];
__device__ __align__(16) int   g_part[256];
__device__ __align__(16) int   g_ssrc[N_EDGES];
__device__ __align__(16) int   g_sidx[N_EDGES];                // nearest table idx
__device__ __align__(16) float g_gout[NGRAPHS];

__device__ __forceinline__ unsigned short f2bfbits(float x){
    union { float f; unsigned int i; } v; v.f = x;
    unsigned int lsb = (v.i >> 16) & 1;
    v.i += 0x7fff + lsb;                      // RNE to bf16
    return (unsigned short)(v.i >> 16);
}
__device__ __forceinline__ float bf2f(unsigned short u){
    union { unsigned int i; float f; } v; v.i = ((unsigned int)u) << 16; return v.f;
}
// exact ShiftedSoftplus (precompute paths)
__device__ __forceinline__ float sspf(float x){
    return fmaxf(x, 0.0f) + log1pf(__expf(-fabsf(x))) - 0.69314718055994530942f;
}
// fast ShiftedSoftplus: ln((1+e^x)/2); exact tails, safe for |x| < 87
__device__ __forceinline__ float sspf_fast(float x){
    return __logf(fmaf(0.5f, __expf(x), 0.5f));
}

// ---------------- counting sort of edges by dst ------------------------------
__global__ __launch_bounds__(256) void zero_cnt_kernel(){
    int i = blockIdx.x * 256 + threadIdx.x;
    g_cnt[i] = 0;                                   // NPAD exact
    if (blockIdx.x == 0 && threadIdx.x < NGRAPHS) g_gout[threadIdx.x] = 0.0f;
}
__global__ __launch_bounds__(256) void hist_kernel(const int* __restrict__ dst){
    int e = blockIdx.x * 256 + threadIdx.x;         // 2500*256 exact
    atomicAdd(&g_cnt[dst[e]], 1);
}
__global__ __launch_bounds__(256) void scan1_kernel(){
    __shared__ int s[256];
    int b = blockIdx.x, t = threadIdx.x, i = b * 256 + t;
    int c = g_cnt[i];
    s[t] = c; __syncthreads();
    #pragma unroll
    for (int off = 1; off < 256; off <<= 1){
        int v = (t >= off) ? s[t - off] : 0; __syncthreads();
        s[t] += v; __syncthreads();
    }
    g_ex[i] = s[t] - c;
    if (t == 255) g_part[b] = s[255];
}
__global__ __launch_bounds__(256) void scan2_kernel(){
    __shared__ int s[256];
    int t = threadIdx.x;
    s[t] = (t < 196) ? g_part[t] : 0; __syncthreads();
    #pragma unroll
    for (int off = 1; off < 256; off <<= 1){
        int v = (t >= off) ? s[t - off] : 0; __syncthreads();
        s[t] += v; __syncthreads();
    }
    g_part[t] = s[t];
}
__global__ __launch_bounds__(256) void scan3_kernel(){
    int b = blockIdx.x, i = b * 256 + threadIdx.x;
    g_row[i] = g_ex[i] + (b > 0 ? g_part[b - 1] : 0);
}
__global__ __launch_bounds__(256) void scatter_kernel(
    const float* __restrict__ pos, const int* __restrict__ src,
    const int* __restrict__ dst)
{
    int e = blockIdx.x * 256 + threadIdx.x;         // exact
    int sv = src[e], dv = dst[e];
    float dx = pos[3*dv]   - pos[3*sv];
    float dy = pos[3*dv+1] - pos[3*sv+1];
    float dz = pos[3*dv+2] - pos[3*sv+2];
    float d = sqrtf(dx*dx + dy*dy + dz*dz);         // < sqrt(3) < DMAX
    int p = atomicAdd(&g_row[dv], 1);               // g_row[v] ends at end-offset
    g_ssrc[p] = sv;
    g_sidx[p] = (int)(d * ((float)(NT - 1) / DMAX) + 0.5f);  // nearest
}

// ---------------- per-layer filter table: 8 points/block, w2 row-reuse ------
__global__ __launch_bounds__(128) void table_kernel(
    const float* __restrict__ w1g, const float* __restrict__ b1g,
    const float* __restrict__ w2g, const float* __restrict__ b2g)
{
    int bid = blockIdx.x;                           // 3 * NT/TPTS blocks
    int l = bid / (NT / TPTS);
    int pt0 = (bid % (NT / TPTS)) * TPTS;
    int n = threadIdx.x;
    __shared__ __align__(16) float w1s[50 * 128];   // 25.6 KB
    __shared__ float ea[TPTS][50];
    __shared__ float tm[TPTS][128];
    __shared__ float Cv[TPTS];
    for (int i = n; i < 50 * 128; i += 128) w1s[i] = w1g[(size_t)l * 50 * 128 + i];
    if (n < 50){
        const float step = 5.0f / 49.0f;
        #pragma unroll
        for (int p = 0; p < TPTS; p++){
            float d = (pt0 + p) * (DMAX / (float)(NT - 1));
            float srel = d * 0.2f;
            float env = expf(1.0f - 1.0f / (1.0f - srel * srel));
            float dd = d - step * (float)n;
            ea[p][n] = expf((-0.5f / (step * step)) * dd * dd) * env;
        }
    }
    if (n < TPTS){
        float d = (pt0 + n) * (DMAX / (float)(NT - 1));
        Cv[n] = 0.5f * (cosf(d * 0.62831853071795864769f) + 1.0f);
    }
    __syncthreads();
    float b1v = b1g[l * 128 + n];
    #pragma unroll
    for (int p = 0; p < TPTS; p++){
        float acc = b1v;
        #pragma unroll 10
        for (int k = 0; k < 50; k++) acc = fmaf(ea[p][k], w1s[k * 128 + n], acc);
        tm[p][n] = sspf(acc);
    }
    __syncthreads();
    float b2v = b2g[l * 128 + n];
    float acc2[TPTS];
    #pragma unroll
    for (int p = 0; p < TPTS; p++) acc2[p] = b2v;
    const float* w2 = w2g + (size_t)l * 128 * 128;
    for (int k = 0; k < 128; k++){
        float wv = w2[k * 128 + n];                 // 1 global read, 8 FMA reuse
        #pragma unroll
        for (int p = 0; p < TPTS; p++) acc2[p] = fmaf(tm[p][k], wv, acc2[p]);
    }
    #pragma unroll
    for (int p = 0; p < TPTS; p++)
        g_table[((size_t)l * NT + pt0 + p) * 128 + n] = f2bfbits(acc2[p] * Cv[p]);
}

// ---------------- weight prep: bf16 transpose of 9 node matrices ------------
__global__ __launch_bounds__(256) void wprep_kernel(
    const float* __restrict__ c1, const float* __restrict__ c2,
    const float* __restrict__ lwp)
{
    int gid = blockIdx.x * 256 + threadIdx.x;       // 576*256 = 147456 exact
    int mat = gid >> 14, r = gid & 16383;
    int n = r & 127, k = r >> 7;
    int l = mat / 3, w = mat % 3;
    const float* base = (w == 0 ? c1 : w == 1 ? c2 : lwp) + (size_t)l * HID * HID;
    g_wT[(size_t)mat * HID * HID + n * 128 + k] = f2bfbits(base[k * 128 + n]);
}

// out1_w [128][64] -> bf16 [n=64][k=128]
__global__ __launch_bounds__(256) void wprep2_kernel(const float* __restrict__ w1g){
    int gid = blockIdx.x * 256 + threadIdx.x;       // 32*256 = 8192 exact
    int n = gid & 63, k = gid >> 6;
    g_w1hT[n * 128 + k] = f2bfbits(w1g[k * 64 + n]);
}

// ---------------- layer-0 conv1: emb gather + h init + GEMM -----------------
__global__ __launch_bounds__(256) void conv1_kernel(
    const int* __restrict__ z, const float* __restrict__ emb)
{
    __shared__ __align__(16) unsigned short a_s[32 * 128];    // 8 KB
    __shared__ int zl[32];
    int tid = threadIdx.x;
    int wave = tid >> 6, lane = tid & 63, quad = lane >> 4, l16 = lane & 15;
    int mtile = (wave & 1) * 16, nbase = (wave >> 1) * 64;
    for (int t = blockIdx.x; t < NTILES; t += gridDim.x){
        int base = t * 32;
        __syncthreads();
        if (tid < 32) zl[tid] = (base + tid < N_NODES) ? z[base + tid] : 0;
        __syncthreads();
        for (int i = tid; i < 512; i += 256){
            int nn = i >> 4, c = i & 15, node = base + nn;
            int phys = c ^ (nn & 15);
            uint4 q = {0u, 0u, 0u, 0u};
            if (node < N_NODES){
                const float* p = &emb[(size_t)zl[nn] * 128 + c * 8];
                float4 f0 = *(const float4*)p;
                float4 f1 = *(const float4*)(p + 4);
                *(float4*)&g_h[(size_t)node * 128 + c * 8]     = f0;
                *(float4*)&g_h[(size_t)node * 128 + c * 8 + 4] = f1;
                q.x = (unsigned int)f2bfbits(f0.x) | ((unsigned int)f2bfbits(f0.y) << 16);
                q.y = (unsigned int)f2bfbits(f0.z) | ((unsigned int)f2bfbits(f0.w) << 16);
                q.z = (unsigned int)f2bfbits(f1.x) | ((unsigned int)f2bfbits(f1.y) << 16);
                q.w = (unsigned int)f2bfbits(f1.z) | ((unsigned int)f2bfbits(f1.w) << 16);
            }
            *(uint4*)&a_s[nn * 128 + phys * 8] = q;
        }
        __syncthreads();
        bf16x8 av[4];
        int arow = mtile + l16;
        #pragma unroll
        for (int ks = 0; ks < 4; ks++){
            int phys = (ks * 4 + quad) ^ (arow & 15);
            av[ks] = *(const bf16x8*)&a_s[arow * 128 + phys * 8];
        }
        f32x4 acc[4] = {};
        #pragma unroll
        for (int nt = 0; nt < 4; nt++){
            int n = nbase + nt * 16 + l16;
            #pragma unroll
            for (int ks = 0; ks < 4; ks++){
                bf16x8 bv = *(const bf16x8*)&g_wT[n * 128 + ks * 32 + quad * 8];
                acc[nt] = __builtin_amdgcn_mfma_f32_16x16x32_bf16(av[ks], bv, acc[nt], 0, 0, 0);
            }
        }
        #pragma unroll
        for (int nt = 0; nt < 4; nt++){
            int n = nbase + nt * 16 + l16;
            #pragma unroll
            for (int r = 0; r < 4; r++){
                int node = base + mtile + quad * 4 + r;
                if (node < N_NODES)
                    g_xfb[(size_t)node * 128 + n] = f2bfbits(acc[nt][r]);
            }
        }
    }
}

// ---------------- wave-autonomous fused GEMM chain (16-node tiles) ----------
// __launch_bounds__(256,3): VGPR cap ~170 -> deeper load prefetch; grid puts
// only ~3 waves/SIMD anyway, so the extra registers are free parallelism.
__global__ __launch_bounds__(256, 3) void fused_kernel(
    int l, const float* __restrict__ bias2, const float* __restrict__ biasl,
    int skip3)
{
    __shared__ __align__(16) unsigned short t_sl[4][16 * 128];  // 16 KB
    int tid = threadIdx.x;
    int wave = tid >> 6, lane = tid & 63, quad = lane >> 4, l16 = lane & 15;
    const unsigned short* c2  = g_wT + (size_t)(l * 3 + 1) * HID * HID;
    const unsigned short* lw  = g_wT + (size_t)(l * 3 + 2) * HID * HID;
    const unsigned short* c1n = g_wT + (size_t)((l + 1) * 3) * HID * HID;
    unsigned short* ts = t_sl[wave];

    int wt = blockIdx.x * 4 + wave;            // 782*4 = 3128 >= NWT
    if (wt >= NWT) return;
    int base = wt * 16;

    float b2r[8], blr[8];
    #pragma unroll
    for (int nt = 0; nt < 8; nt++){
        b2r[nt] = bias2[nt * 16 + l16];
        blr[nt] = biasl[nt * 16 + l16];
    }

    // ---- GEMM1: acc = aggb(tile) @ c2   (A direct from global, B from L2)
    bf16x8 av[4];
    #pragma unroll
    for (int ks = 0; ks < 4; ks++)
        av[ks] = *(const bf16x8*)&g_aggb[(size_t)(base + l16) * 128 + ks * 32 + quad * 8];
    f32x4 acc[8] = {};
    #pragma unroll
    for (int nt = 0; nt < 8; nt++){
        int n = nt * 16 + l16;
        #pragma unroll
        for (int ks = 0; ks < 4; ks++){
            bf16x8 bv = *(const bf16x8*)&c2[n * 128 + ks * 32 + quad * 8];
            acc[nt] = __builtin_amdgcn_mfma_f32_16x16x32_bf16(av[ks], bv, acc[nt], 0, 0, 0);
        }
    }
    // epilogue1: t = ssp(acc + b2) -> ts (swizzled; wave-internal ordering)
    #pragma unroll
    for (int nt = 0; nt < 8; nt++){
        int col = nt * 16 + l16;
        int c = col >> 3, sub = col & 7;
        #pragma unroll
        for (int r = 0; r < 4; r++){
            int row = quad * 4 + r;
            ts[row * 128 + ((c ^ row) & 15) * 8 + sub] =
                f2bfbits(sspf_fast(acc[nt][r] + b2r[nt]));
        }
    }

    // ---- GEMM2: acc2 = t @ lw
    #pragma unroll
    for (int ks = 0; ks < 4; ks++){
        int phys = (ks * 4 + quad) ^ l16;
        av[ks] = *(const bf16x8*)&ts[l16 * 128 + phys * 8];
    }
    f32x4 acc2[8] = {};
    #pragma unroll
    for (int nt = 0; nt < 8; nt++){
        int n = nt * 16 + l16;
        #pragma unroll
        for (int ks = 0; ks < 4; ks++){
            bf16x8 bv = *(const bf16x8*)&lw[n * 128 + ks * 32 + quad * 8];
            acc2[nt] = __builtin_amdgcn_mfma_f32_16x16x32_bf16(av[ks], bv, acc2[nt], 0, 0, 0);
        }
    }
    // epilogue2: h += acc2 + lb; stash bf16(h) into ts for GEMM3
    #pragma unroll
    for (int nt = 0; nt < 8; nt++){
        int col = nt * 16 + l16;
        int c = col >> 3, sub = col & 7;
        #pragma unroll
        for (int r = 0; r < 4; r++){
            int row = quad * 4 + r;
            size_t o = (size_t)(base + row) * 128 + col;
            float hv = g_h[o] + acc2[nt][r] + blr[nt];
            g_h[o] = hv;
            if (!skip3)
                ts[row * 128 + ((c ^ row) & 15) * 8 + sub] = f2bfbits(hv);
        }
    }
    if (skip3) return;

    // ---- GEMM3: xfb = bf16(h) @ c1next
    #pragma unroll
    for (int ks = 0; ks < 4; ks++){
        int phys = (ks * 4 + quad) ^ l16;
        av[ks] = *(const bf16x8*)&ts[l16 * 128 + phys * 8];
    }
    f32x4 acc3[8] = {};
    #pragma unroll
    for (int nt = 0; nt < 8; nt++){
        int n = nt * 16 + l16;
        #pragma unroll
        for (int ks = 0; ks < 4; ks++){
            bf16x8 bv = *(const bf16x8*)&c1n[n * 128 + ks * 32 + quad * 8];
            acc3[nt] = __builtin_amdgcn_mfma_f32_16x16x32_bf16(av[ks], bv, acc3[nt], 0, 0, 0);
        }
    }
    #pragma unroll
    for (int nt = 0; nt < 8; nt++){
        int col = nt * 16 + l16;
        #pragma unroll
        for (int r = 0; r < 4; r++){
            int row = quad * 4 + r;
            g_xfb[(size_t)(base + row) * 128 + col] = f2bfbits(acc3[nt][r]);
        }
    }
}

// ---------------- CSR edge aggregation: bf16 nearest-table, 4-edge unroll ---
__global__ __launch_bounds__(256) void agg_kernel(int l){
    const unsigned short* __restrict__ T = g_table + (size_t)l * NT * 128;
    int tid = threadIdx.x;
    int grp = tid >> 5, n0 = (tid & 31) * 4;
    int v = blockIdx.x * 8 + grp;                   // 6250 blocks * 8 = 50000 exact
    int e1 = g_row[v];
    int e0 = e1 - g_cnt[v];
    float a0 = 0.f, a1 = 0.f, a2 = 0.f, a3 = 0.f;
    int j = e0;
    for (; j + 4 <= e1; j += 4){
        int sA = g_ssrc[j],   sB = g_ssrc[j+1];
        int sC = g_ssrc[j+2], sD = g_ssrc[j+3];
        int iA = g_sidx[j],   iB = g_sidx[j+1];
        int iC = g_sidx[j+2], iD = g_sidx[j+3];
        ushort4 tA = *(const ushort4*)&T[(size_t)iA * 128 + n0];
        ushort4 tB = *(const ushort4*)&T[(size_t)iB * 128 + n0];
        ushort4 tC = *(const ushort4*)&T[(size_t)iC * 128 + n0];
        ushort4 tD = *(const ushort4*)&T[(size_t)iD * 128 + n0];
        ushort4 gA = *(const ushort4*)&g_xfb[(size_t)sA * 128 + n0];
        ushort4 gB = *(const ushort4*)&g_xfb[(size_t)sB * 128 + n0];
        ushort4 gC = *(const ushort4*)&g_xfb[(size_t)sC * 128 + n0];
        ushort4 gD = *(const ushort4*)&g_xfb[(size_t)sD * 128 + n0];
        a0 = fmaf(bf2f(tA.x), bf2f(gA.x), a0); a1 = fmaf(bf2f(tA.y), bf2f(gA.y), a1);
        a2 = fmaf(bf2f(tA.z), bf2f(gA.z), a2); a3 = fmaf(bf2f(tA.w), bf2f(gA.w), a3);
        a0 = fmaf(bf2f(tB.x), bf2f(gB.x), a0); a1 = fmaf(bf2f(tB.y), bf2f(gB.y), a1);
        a2 = fmaf(bf2f(tB.z), bf2f(gB.z), a2); a3 = fmaf(bf2f(tB.w), bf2f(gB.w), a3);
        a0 = fmaf(bf2f(tC.x), bf2f(gC.x), a0); a1 = fmaf(bf2f(tC.y), bf2f(gC.y), a1);
        a2 = fmaf(bf2f(tC.z), bf2f(gC.z), a2); a3 = fmaf(bf2f(tC.w), bf2f(gC.w), a3);
        a0 = fmaf(bf2f(tD.x), bf2f(gD.x), a0); a1 = fmaf(bf2f(tD.y), bf2f(gD.y), a1);
        a2 = fmaf(bf2f(tD.z), bf2f(gD.z), a2); a3 = fmaf(bf2f(tD.w), bf2f(gD.w), a3);
    }
    for (; j < e1; j++){
        int s = g_ssrc[j], i0 = g_sidx[j];
        ushort4 t0 = *(const ushort4*)&T[(size_t)i0 * 128 + n0];
        ushort4 g = *(const ushort4*)&g_xfb[(size_t)s * 128 + n0];
        a0 = fmaf(bf2f(t0.x), bf2f(g.x), a0); a1 = fmaf(bf2f(t0.y), bf2f(g.y), a1);
        a2 = fmaf(bf2f(t0.z), bf2f(g.z), a2); a3 = fmaf(bf2f(t0.w), bf2f(g.w), a3);
    }
    ushort4 o;
    o.x = f2bfbits(a0); o.y = f2bfbits(a1); o.z = f2bfbits(a2); o.w = f2bfbits(a3);
    *(ushort4*)&g_aggb[(size_t)v * 128 + n0] = o;
}

// ---------------- output head: MFMA GEMM + quad-butterfly + seg-sum ---------
__global__ __launch_bounds__(256) void head_kernel(
    const float* __restrict__ b1g, const float* __restrict__ w2g,
    const float* __restrict__ b2g, const int* __restrict__ batch)
{
    __shared__ float part[NGRAPHS];
    int tid = threadIdx.x;
    int wave = tid >> 6, lane = tid & 63, quad = lane >> 4, l16 = lane & 15;
    if (tid < NGRAPHS) part[tid] = 0.0f;
    __syncthreads();
    float sb2 = b2g[0];

    int wt = blockIdx.x * 4 + wave;            // 782 blocks; 50000 = 3125*16 exact
    if (wt < NWT){
        int base = wt * 16;
        float b1r[4], w2r[4];
        #pragma unroll
        for (int nt = 0; nt < 4; nt++){
            b1r[nt] = b1g[nt * 16 + l16];
            w2r[nt] = w2g[nt * 16 + l16];
        }
        bf16x8 av[4];
        #pragma unroll
        for (int ks = 0; ks < 4; ks++){
            const float* p = &g_h[(size_t)(base + l16) * 128 + ks * 32 + quad * 8];
            float4 f0 = *(const float4*)p;
            float4 f1 = *(const float4*)(p + 4);
            union { unsigned int u[4]; bf16x8 v; } pk;
            pk.u[0] = (unsigned int)f2bfbits(f0.x) | ((unsigned int)f2bfbits(f0.y) << 16);
            pk.u[1] = (unsigned int)f2bfbits(f0.z) | ((unsigned int)f2bfbits(f0.w) << 16);
            pk.u[2] = (unsigned int)f2bfbits(f1.x) | ((unsigned int)f2bfbits(f1.y) << 16);
            pk.u[3] = (unsigned int)f2bfbits(f1.z) | ((unsigned int)f2bfbits(f1.w) << 16);
            av[ks] = pk.v;
        }
        f32x4 acc[4] = {};
        #pragma unroll
        for (int nt = 0; nt < 4; nt++){
            int n = nt * 16 + l16;
            #pragma unroll
            for (int ks = 0; ks < 4; ks++){
                bf16x8 bv = *(const bf16x8*)&g_w1hT[n * 128 + ks * 32 + quad * 8];
                acc[nt] = __builtin_amdgcn_mfma_f32_16x16x32_bf16(av[ks], bv, acc[nt], 0, 0, 0);
            }
        }
        float srow[4];
        #pragma unroll
        for (int r = 0; r < 4; r++){
            float s = 0.0f;
            #pragma unroll
            for (int nt = 0; nt < 4; nt++)
                s += sspf_fast(acc[nt][r] + b1r[nt]) * w2r[nt];
            #pragma unroll
            for (int off = 1; off < 16; off <<= 1)
                s += __shfl_xor(s, off, 64);
            srow[r] = s;
        }
        if (l16 == 0){
            #pragma unroll
            for (int r = 0; r < 4; r++){
                int node = base + quad * 4 + r;
                atomicAdd(&part[batch[node]], srow[r] + sb2);
            }
        }
    }
    __syncthreads();
    if (tid < NGRAPHS && part[tid] != 0.0f)
        __hip_atomic_fetch_add(&g_gout[tid], part[tid],
                               __ATOMIC_RELAXED, __HIP_MEMORY_SCOPE_AGENT);
}

__global__ void store_kernel(float* __restrict__ out){
    int i = threadIdx.x;
    if (i < NGRAPHS) out[i] = g_gout[i];
}

extern "C" void kernel_launch(void* const* d_in, const int* in_sizes, int n_in,
                              void* d_out, int out_size, void* d_ws, size_t ws_size,
                              hipStream_t stream)
{
    const int* z       = (const int*)d_in[0];
    const float* pos   = (const float*)d_in[1];
    const int* ei      = (const int*)d_in[2];
    const int* src = ei;
    const int* dst = ei + N_EDGES;
    const int* batch   = (const int*)d_in[3];
    const float* emb     = (const float*)d_in[4];
    const float* mlp_w1  = (const float*)d_in[5];
    const float* mlp_b1  = (const float*)d_in[6];
    const float* mlp_w2  = (const float*)d_in[7];
    const float* mlp_b2  = (const float*)d_in[8];
    const float* conv1_w = (const float*)d_in[9];
    const float* conv2_w = (const float*)d_in[10];
    const float* conv2_b = (const float*)d_in[11];
    const float* lin_w   = (const float*)d_in[12];
    const float* lin_b   = (const float*)d_in[13];
    const float* out1_w  = (const float*)d_in[14];
    const float* out1_b  = (const float*)d_in[15];
    const float* out2_w  = (const float*)d_in[16];
    const float* out2_b  = (const float*)d_in[17];
    (void)d_ws; (void)ws_size; (void)in_sizes; (void)n_in; (void)out_size;

    // --- one-time: CSR sort, tables, weight prep ---
    zero_cnt_kernel<<<196, 256, 0, stream>>>();
    hist_kernel<<<2500, 256, 0, stream>>>(dst);
    scan1_kernel<<<196, 256, 0, stream>>>();
    scan2_kernel<<<1, 256, 0, stream>>>();
    scan3_kernel<<<196, 256, 0, stream>>>();
    scatter_kernel<<<2500, 256, 0, stream>>>(pos, src, dst);
    table_kernel<<<NL * (NT / TPTS), 128, 0, stream>>>(mlp_w1, mlp_b1, mlp_w2, mlp_b2);
    wprep_kernel<<<576, 256, 0, stream>>>(conv1_w, conv2_w, lin_w);
    wprep2_kernel<<<32, 256, 0, stream>>>(out1_w);

    conv1_kernel<<<NTILES, 256, 0, stream>>>(z, emb);  // h init + layer-0 conv1
    for (int l = 0; l < NL; l++){
        agg_kernel<<<6250, 256, 0, stream>>>(l);
        fused_kernel<<<(NWT + 3) / 4, 256, 0, stream>>>(l, conv2_b + (size_t)l * HID,
                                                        lin_b + (size_t)l * HID, l == NL - 1);
    }

    head_kernel<<<(NWT + 3) / 4, 256, 0, stream>>>(out1_b, out2_w, out2_b, batch);
    store_kernel<<<1, 64, 0, stream>>>((float*)d_out);
}

// Round 17
// 491.469 us; speedup vs baseline: 1.5249x; 1.0373x over previous
//
#include <hip/hip_runtime.h>
#include <math.h>

#define N_NODES 50000
#define N_EDGES 640000
#define HID 128
#define NL 3
#define NGRAPHS 64
#define NT 4096
#define TPTS 8
#define DMAX 1.7330f
#define NPAD 50176   // 196*256
#define NTILES 1563  // ceil(50000/32)
#define NWT 3125     // 50000/16 wave-tiles
#define GRID_F2 391  // ceil(NWT/8): 2 tiles per wave

typedef __attribute__((ext_vector_type(8))) short bf16x8;
typedef __attribute__((ext_vector_type(4))) float f32x4;

// ---------------- module-scope device buffers -------------------------------
__device__ __align__(16) float g_h  [N_NODES * HID];           // f32 node features
__device__ __align__(16) unsigned short g_xfb [N_NODES * HID]; // bf16 xf
__device__ __align__(16) unsigned short g_aggb[N_NODES * HID]; // bf16 aggregation
__device__ __align__(16) unsigned short g_table[NL * NT * HID];// bf16 W(d)*C(d), 3 MB
__device__ __align__(16) unsigned short g_wT[9 * HID * HID];   // bf16 [n][k]
__device__ __align__(16) unsigned short g_w1hT[64 * HID];      // bf16 out1_w [n][k]
__device__ __align__(16) int   g_cnt[NPAD];
__device__ __align__(16) int   g_ex [NPAD];
__device__ __align__(16) int   g_row[NPAD];
__device__ __align__(16) int   g_part[256];
__device__ __align__(16) int   g_ssrc[N_EDGES];
__device__ __align__(16) int   g_sidx[N_EDGES];                // nearest table idx
__device__ __align__(16) float g_gout[NGRAPHS];

__device__ __forceinline__ unsigned short f2bfbits(float x){
    union { float f; unsigned int i; } v; v.f = x;
    unsigned int lsb = (v.i >> 16) & 1;
    v.i += 0x7fff + lsb;                      // RNE to bf16
    return (unsigned short)(v.i >> 16);
}
__device__ __forceinline__ float bf2f(unsigned short u){
    union { unsigned int i; float f; } v; v.i = ((unsigned int)u) << 16; return v.f;
}
// exact ShiftedSoftplus (precompute paths)
__device__ __forceinline__ float sspf(float x){
    return fmaxf(x, 0.0f) + log1pf(__expf(-fabsf(x))) - 0.69314718055994530942f;
}
// fast ShiftedSoftplus: ln((1+e^x)/2); exact tails, safe for |x| < 87
__device__ __forceinline__ float sspf_fast(float x){
    return __logf(fmaf(0.5f, __expf(x), 0.5f));
}

// ---------------- counting sort of edges by dst ------------------------------
__global__ __launch_bounds__(256) void zero_cnt_kernel(){
    int i = blockIdx.x * 256 + threadIdx.x;
    g_cnt[i] = 0;                                   // NPAD exact
    if (blockIdx.x == 0 && threadIdx.x < NGRAPHS) g_gout[threadIdx.x] = 0.0f;
}
__global__ __launch_bounds__(256) void hist_kernel(const int* __restrict__ dst){
    int e = blockIdx.x * 256 + threadIdx.x;         // 2500*256 exact
    atomicAdd(&g_cnt[dst[e]], 1);
}
__global__ __launch_bounds__(256) void scan1_kernel(){
    __shared__ int s[256];
    int b = blockIdx.x, t = threadIdx.x, i = b * 256 + t;
    int c = g_cnt[i];
    s[t] = c; __syncthreads();
    #pragma unroll
    for (int off = 1; off < 256; off <<= 1){
        int v = (t >= off) ? s[t - off] : 0; __syncthreads();
        s[t] += v; __syncthreads();
    }
    g_ex[i] = s[t] - c;
    if (t == 255) g_part[b] = s[255];
}
__global__ __launch_bounds__(256) void scan2_kernel(){
    __shared__ int s[256];
    int t = threadIdx.x;
    s[t] = (t < 196) ? g_part[t] : 0; __syncthreads();
    #pragma unroll
    for (int off = 1; off < 256; off <<= 1){
        int v = (t >= off) ? s[t - off] : 0; __syncthreads();
        s[t] += v; __syncthreads();
    }
    g_part[t] = s[t];
}
__global__ __launch_bounds__(256) void scan3_kernel(){
    int b = blockIdx.x, i = b * 256 + threadIdx.x;
    g_row[i] = g_ex[i] + (b > 0 ? g_part[b - 1] : 0);
}
__global__ __launch_bounds__(256) void scatter_kernel(
    const float* __restrict__ pos, const int* __restrict__ src,
    const int* __restrict__ dst)
{
    int e = blockIdx.x * 256 + threadIdx.x;         // exact
    int sv = src[e], dv = dst[e];
    float dx = pos[3*dv]   - pos[3*sv];
    float dy = pos[3*dv+1] - pos[3*sv+1];
    float dz = pos[3*dv+2] - pos[3*sv+2];
    float d = sqrtf(dx*dx + dy*dy + dz*dz);         // < sqrt(3) < DMAX
    int p = atomicAdd(&g_row[dv], 1);               // g_row[v] ends at end-offset
    g_ssrc[p] = sv;
    g_sidx[p] = (int)(d * ((float)(NT - 1) / DMAX) + 0.5f);  // nearest
}

// ---------------- per-layer filter table: 8 points/block, w2 row-reuse ------
__global__ __launch_bounds__(128) void table_kernel(
    const float* __restrict__ w1g, const float* __restrict__ b1g,
    const float* __restrict__ w2g, const float* __restrict__ b2g)
{
    int bid = blockIdx.x;                           // 3 * NT/TPTS blocks
    int l = bid / (NT / TPTS);
    int pt0 = (bid % (NT / TPTS)) * TPTS;
    int n = threadIdx.x;
    __shared__ __align__(16) float w1s[50 * 128];   // 25.6 KB
    __shared__ float ea[TPTS][50];
    __shared__ float tm[TPTS][128];
    __shared__ float Cv[TPTS];
    for (int i = n; i < 50 * 128; i += 128) w1s[i] = w1g[(size_t)l * 50 * 128 + i];
    if (n < 50){
        const float step = 5.0f / 49.0f;
        #pragma unroll
        for (int p = 0; p < TPTS; p++){
            float d = (pt0 + p) * (DMAX / (float)(NT - 1));
            float srel = d * 0.2f;
            float env = expf(1.0f - 1.0f / (1.0f - srel * srel));
            float dd = d - step * (float)n;
            ea[p][n] = expf((-0.5f / (step * step)) * dd * dd) * env;
        }
    }
    if (n < TPTS){
        float d = (pt0 + n) * (DMAX / (float)(NT - 1));
        Cv[n] = 0.5f * (cosf(d * 0.62831853071795864769f) + 1.0f);
    }
    __syncthreads();
    float b1v = b1g[l * 128 + n];
    #pragma unroll
    for (int p = 0; p < TPTS; p++){
        float acc = b1v;
        #pragma unroll 10
        for (int k = 0; k < 50; k++) acc = fmaf(ea[p][k], w1s[k * 128 + n], acc);
        tm[p][n] = sspf(acc);
    }
    __syncthreads();
    float b2v = b2g[l * 128 + n];
    float acc2[TPTS];
    #pragma unroll
    for (int p = 0; p < TPTS; p++) acc2[p] = b2v;
    const float* w2 = w2g + (size_t)l * 128 * 128;
    for (int k = 0; k < 128; k++){
        float wv = w2[k * 128 + n];                 // 1 global read, 8 FMA reuse
        #pragma unroll
        for (int p = 0; p < TPTS; p++) acc2[p] = fmaf(tm[p][k], wv, acc2[p]);
    }
    #pragma unroll
    for (int p = 0; p < TPTS; p++)
        g_table[((size_t)l * NT + pt0 + p) * 128 + n] = f2bfbits(acc2[p] * Cv[p]);
}

// ---------------- weight prep: bf16 transpose of 9 node matrices ------------
__global__ __launch_bounds__(256) void wprep_kernel(
    const float* __restrict__ c1, const float* __restrict__ c2,
    const float* __restrict__ lwp)
{
    int gid = blockIdx.x * 256 + threadIdx.x;       // 576*256 = 147456 exact
    int mat = gid >> 14, r = gid & 16383;
    int n = r & 127, k = r >> 7;
    int l = mat / 3, w = mat % 3;
    const float* base = (w == 0 ? c1 : w == 1 ? c2 : lwp) + (size_t)l * HID * HID;
    g_wT[(size_t)mat * HID * HID + n * 128 + k] = f2bfbits(base[k * 128 + n]);
}

// out1_w [128][64] -> bf16 [n=64][k=128]
__global__ __launch_bounds__(256) void wprep2_kernel(const float* __restrict__ w1g){
    int gid = blockIdx.x * 256 + threadIdx.x;       // 32*256 = 8192 exact
    int n = gid & 63, k = gid >> 6;
    g_w1hT[n * 128 + k] = f2bfbits(w1g[k * 64 + n]);
}

// ---------------- layer-0 conv1: emb gather + h init + GEMM -----------------
__global__ __launch_bounds__(256) void conv1_kernel(
    const int* __restrict__ z, const float* __restrict__ emb)
{
    __shared__ __align__(16) unsigned short a_s[32 * 128];    // 8 KB
    __shared__ int zl[32];
    int tid = threadIdx.x;
    int wave = tid >> 6, lane = tid & 63, quad = lane >> 4, l16 = lane & 15;
    int mtile = (wave & 1) * 16, nbase = (wave >> 1) * 64;
    for (int t = blockIdx.x; t < NTILES; t += gridDim.x){
        int base = t * 32;
        __syncthreads();
        if (tid < 32) zl[tid] = (base + tid < N_NODES) ? z[base + tid] : 0;
        __syncthreads();
        for (int i = tid; i < 512; i += 256){
            int nn = i >> 4, c = i & 15, node = base + nn;
            int phys = c ^ (nn & 15);
            uint4 q = {0u, 0u, 0u, 0u};
            if (node < N_NODES){
                const float* p = &emb[(size_t)zl[nn] * 128 + c * 8];
                float4 f0 = *(const float4*)p;
                float4 f1 = *(const float4*)(p + 4);
                *(float4*)&g_h[(size_t)node * 128 + c * 8]     = f0;
                *(float4*)&g_h[(size_t)node * 128 + c * 8 + 4] = f1;
                q.x = (unsigned int)f2bfbits(f0.x) | ((unsigned int)f2bfbits(f0.y) << 16);
                q.y = (unsigned int)f2bfbits(f0.z) | ((unsigned int)f2bfbits(f0.w) << 16);
                q.z = (unsigned int)f2bfbits(f1.x) | ((unsigned int)f2bfbits(f1.y) << 16);
                q.w = (unsigned int)f2bfbits(f1.z) | ((unsigned int)f2bfbits(f1.w) << 16);
            }
            *(uint4*)&a_s[nn * 128 + phys * 8] = q;
        }
        __syncthreads();
        bf16x8 av[4];
        int arow = mtile + l16;
        #pragma unroll
        for (int ks = 0; ks < 4; ks++){
            int phys = (ks * 4 + quad) ^ (arow & 15);
            av[ks] = *(const bf16x8*)&a_s[arow * 128 + phys * 8];
        }
        f32x4 acc[4] = {};
        #pragma unroll
        for (int nt = 0; nt < 4; nt++){
            int n = nbase + nt * 16 + l16;
            #pragma unroll
            for (int ks = 0; ks < 4; ks++){
                bf16x8 bv = *(const bf16x8*)&g_wT[n * 128 + ks * 32 + quad * 8];
                acc[nt] = __builtin_amdgcn_mfma_f32_16x16x32_bf16(av[ks], bv, acc[nt], 0, 0, 0);
            }
        }
        #pragma unroll
        for (int nt = 0; nt < 4; nt++){
            int n = nbase + nt * 16 + l16;
            #pragma unroll
            for (int r = 0; r < 4; r++){
                int node = base + mtile + quad * 4 + r;
                if (node < N_NODES)
                    g_xfb[(size_t)node * 128 + n] = f2bfbits(acc[nt][r]);
            }
        }
    }
}

// ---------------- fused GEMM chain: 2 independent 16-node tiles per wave ----
// B fragments loaded once, fed to both tiles (halves per-node weight stream);
// the two tiles give two independent MFMA chains -> 2x latency hiding.
__global__ __launch_bounds__(256, 2) void fused_kernel(
    int l, const float* __restrict__ bias2, const float* __restrict__ biasl,
    int skip3)
{
    __shared__ __align__(16) unsigned short t_sl[4][2][16 * 128];  // 32 KB
    int tid = threadIdx.x;
    int wave = tid >> 6, lane = tid & 63, quad = lane >> 4, l16 = lane & 15;
    const unsigned short* c2  = g_wT + (size_t)(l * 3 + 1) * HID * HID;
    const unsigned short* lw  = g_wT + (size_t)(l * 3 + 2) * HID * HID;
    const unsigned short* c1n = g_wT + (size_t)((l + 1) * 3) * HID * HID;

    int wv = blockIdx.x * 4 + wave;            // 391*4 = 1564 waves
    int wt0 = wv * 2;                          // tiles wt0, wt0+1 (3128 >= NWT)
    int base[2]; bool valid[2];
    #pragma unroll
    for (int p = 0; p < 2; p++){
        int wt = wt0 + p;
        valid[p] = wt < NWT;
        base[p] = (valid[p] ? wt : NWT - 1) * 16;   // clamp: loads stay in-bounds
    }

    float b2r[8], blr[8];
    #pragma unroll
    for (int nt = 0; nt < 8; nt++){
        b2r[nt] = bias2[nt * 16 + l16];
        blr[nt] = biasl[nt * 16 + l16];
    }

    // ---- GEMM1 (both tiles): acc = aggb @ c2, B shared
    bf16x8 av[2][4];
    #pragma unroll
    for (int p = 0; p < 2; p++)
        #pragma unroll
        for (int ks = 0; ks < 4; ks++)
            av[p][ks] = *(const bf16x8*)&g_aggb[(size_t)(base[p] + l16) * 128 + ks * 32 + quad * 8];
    f32x4 acc0[8] = {}, acc1[8] = {};
    #pragma unroll
    for (int nt = 0; nt < 8; nt++){
        int n = nt * 16 + l16;
        #pragma unroll
        for (int ks = 0; ks < 4; ks++){
            bf16x8 bv = *(const bf16x8*)&c2[n * 128 + ks * 32 + quad * 8];
            acc0[nt] = __builtin_amdgcn_mfma_f32_16x16x32_bf16(av[0][ks], bv, acc0[nt], 0, 0, 0);
            acc1[nt] = __builtin_amdgcn_mfma_f32_16x16x32_bf16(av[1][ks], bv, acc1[nt], 0, 0, 0);
        }
    }
    // epilogue1: t = ssp(acc + b2) -> ts[p]
    #pragma unroll
    for (int nt = 0; nt < 8; nt++){
        int col = nt * 16 + l16;
        int c = col >> 3, sub = col & 7;
        #pragma unroll
        for (int r = 0; r < 4; r++){
            int row = quad * 4 + r;
            int off = row * 128 + ((c ^ row) & 15) * 8 + sub;
            t_sl[wave][0][off] = f2bfbits(sspf_fast(acc0[nt][r] + b2r[nt]));
            t_sl[wave][1][off] = f2bfbits(sspf_fast(acc1[nt][r] + b2r[nt]));
        }
    }

    // ---- GEMM2 (both): acc2 = t @ lw, B shared
    #pragma unroll
    for (int p = 0; p < 2; p++)
        #pragma unroll
        for (int ks = 0; ks < 4; ks++){
            int phys = (ks * 4 + quad) ^ l16;
            av[p][ks] = *(const bf16x8*)&t_sl[wave][p][l16 * 128 + phys * 8];
        }
    f32x4 acc20[8] = {}, acc21[8] = {};
    #pragma unroll
    for (int nt = 0; nt < 8; nt++){
        int n = nt * 16 + l16;
        #pragma unroll
        for (int ks = 0; ks < 4; ks++){
            bf16x8 bv = *(const bf16x8*)&lw[n * 128 + ks * 32 + quad * 8];
            acc20[nt] = __builtin_amdgcn_mfma_f32_16x16x32_bf16(av[0][ks], bv, acc20[nt], 0, 0, 0);
            acc21[nt] = __builtin_amdgcn_mfma_f32_16x16x32_bf16(av[1][ks], bv, acc21[nt], 0, 0, 0);
        }
    }
    // epilogue2: h += acc2 + lb; stash bf16(h) into ts for GEMM3
    #pragma unroll
    for (int nt = 0; nt < 8; nt++){
        int col = nt * 16 + l16;
        int c = col >> 3, sub = col & 7;
        #pragma unroll
        for (int r = 0; r < 4; r++){
            int row = quad * 4 + r;
            int toff = row * 128 + ((c ^ row) & 15) * 8 + sub;
            if (valid[0]){
                size_t o = (size_t)(base[0] + row) * 128 + col;
                float hv = g_h[o] + acc20[nt][r] + blr[nt];
                g_h[o] = hv;
                if (!skip3) t_sl[wave][0][toff] = f2bfbits(hv);
            }
            if (valid[1]){
                size_t o = (size_t)(base[1] + row) * 128 + col;
                float hv = g_h[o] + acc21[nt][r] + blr[nt];
                g_h[o] = hv;
                if (!skip3) t_sl[wave][1][toff] = f2bfbits(hv);
            }
        }
    }
    if (skip3) return;

    // ---- GEMM3 (both): xfb = bf16(h) @ c1next, B shared
    #pragma unroll
    for (int p = 0; p < 2; p++)
        #pragma unroll
        for (int ks = 0; ks < 4; ks++){
            int phys = (ks * 4 + quad) ^ l16;
            av[p][ks] = *(const bf16x8*)&t_sl[wave][p][l16 * 128 + phys * 8];
        }
    f32x4 acc30[8] = {}, acc31[8] = {};
    #pragma unroll
    for (int nt = 0; nt < 8; nt++){
        int n = nt * 16 + l16;
        #pragma unroll
        for (int ks = 0; ks < 4; ks++){
            bf16x8 bv = *(const bf16x8*)&c1n[n * 128 + ks * 32 + quad * 8];
            acc30[nt] = __builtin_amdgcn_mfma_f32_16x16x32_bf16(av[0][ks], bv, acc30[nt], 0, 0, 0);
            acc31[nt] = __builtin_amdgcn_mfma_f32_16x16x32_bf16(av[1][ks], bv, acc31[nt], 0, 0, 0);
        }
    }
    #pragma unroll
    for (int nt = 0; nt < 8; nt++){
        int col = nt * 16 + l16;
        #pragma unroll
        for (int r = 0; r < 4; r++){
            int row = quad * 4 + r;
            if (valid[0])
                g_xfb[(size_t)(base[0] + row) * 128 + col] = f2bfbits(acc30[nt][r]);
            if (valid[1])
                g_xfb[(size_t)(base[1] + row) * 128 + col] = f2bfbits(acc31[nt][r]);
        }
    }
}

// ---------------- CSR edge aggregation: bf16 nearest-table, 4-edge unroll ---
__global__ __launch_bounds__(256) void agg_kernel(int l){
    const unsigned short* __restrict__ T = g_table + (size_t)l * NT * 128;
    int tid = threadIdx.x;
    int grp = tid >> 5, n0 = (tid & 31) * 4;
    int v = blockIdx.x * 8 + grp;                   // 6250 blocks * 8 = 50000 exact
    int e1 = g_row[v];
    int e0 = e1 - g_cnt[v];
    float a0 = 0.f, a1 = 0.f, a2 = 0.f, a3 = 0.f;
    int j = e0;
    for (; j + 4 <= e1; j += 4){
        int sA = g_ssrc[j],   sB = g_ssrc[j+1];
        int sC = g_ssrc[j+2], sD = g_ssrc[j+3];
        int iA = g_sidx[j],   iB = g_sidx[j+1];
        int iC = g_sidx[j+2], iD = g_sidx[j+3];
        ushort4 tA = *(const ushort4*)&T[(size_t)iA * 128 + n0];
        ushort4 tB = *(const ushort4*)&T[(size_t)iB * 128 + n0];
        ushort4 tC = *(const ushort4*)&T[(size_t)iC * 128 + n0];
        ushort4 tD = *(const ushort4*)&T[(size_t)iD * 128 + n0];
        ushort4 gA = *(const ushort4*)&g_xfb[(size_t)sA * 128 + n0];
        ushort4 gB = *(const ushort4*)&g_xfb[(size_t)sB * 128 + n0];
        ushort4 gC = *(const ushort4*)&g_xfb[(size_t)sC * 128 + n0];
        ushort4 gD = *(const ushort4*)&g_xfb[(size_t)sD * 128 + n0];
        a0 = fmaf(bf2f(tA.x), bf2f(gA.x), a0); a1 = fmaf(bf2f(tA.y), bf2f(gA.y), a1);
        a2 = fmaf(bf2f(tA.z), bf2f(gA.z), a2); a3 = fmaf(bf2f(tA.w), bf2f(gA.w), a3);
        a0 = fmaf(bf2f(tB.x), bf2f(gB.x), a0); a1 = fmaf(bf2f(tB.y), bf2f(gB.y), a1);
        a2 = fmaf(bf2f(tB.z), bf2f(gB.z), a2); a3 = fmaf(bf2f(tB.w), bf2f(gB.w), a3);
        a0 = fmaf(bf2f(tC.x), bf2f(gC.x), a0); a1 = fmaf(bf2f(tC.y), bf2f(gC.y), a1);
        a2 = fmaf(bf2f(tC.z), bf2f(gC.z), a2); a3 = fmaf(bf2f(tC.w), bf2f(gC.w), a3);
        a0 = fmaf(bf2f(tD.x), bf2f(gD.x), a0); a1 = fmaf(bf2f(tD.y), bf2f(gD.y), a1);
        a2 = fmaf(bf2f(tD.z), bf2f(gD.z), a2); a3 = fmaf(bf2f(tD.w), bf2f(gD.w), a3);
    }
    for (; j < e1; j++){
        int s = g_ssrc[j], i0 = g_sidx[j];
        ushort4 t0 = *(const ushort4*)&T[(size_t)i0 * 128 + n0];
        ushort4 g = *(const ushort4*)&g_xfb[(size_t)s * 128 + n0];
        a0 = fmaf(bf2f(t0.x), bf2f(g.x), a0); a1 = fmaf(bf2f(t0.y), bf2f(g.y), a1);
        a2 = fmaf(bf2f(t0.z), bf2f(g.z), a2); a3 = fmaf(bf2f(t0.w), bf2f(g.w), a3);
    }
    ushort4 o;
    o.x = f2bfbits(a0); o.y = f2bfbits(a1); o.z = f2bfbits(a2); o.w = f2bfbits(a3);
    *(ushort4*)&g_aggb[(size_t)v * 128 + n0] = o;
}

// ---------------- output head: MFMA GEMM + quad-butterfly + seg-sum ---------
__global__ __launch_bounds__(256) void head_kernel(
    const float* __restrict__ b1g, const float* __restrict__ w2g,
    const float* __restrict__ b2g, const int* __restrict__ batch)
{
    __shared__ float part[NGRAPHS];
    int tid = threadIdx.x;
    int wave = tid >> 6, lane = tid & 63, quad = lane >> 4, l16 = lane & 15;
    if (tid < NGRAPHS) part[tid] = 0.0f;
    __syncthreads();
    float sb2 = b2g[0];

    int wt = blockIdx.x * 4 + wave;            // 782 blocks; 50000 = 3125*16 exact
    if (wt < NWT){
        int base = wt * 16;
        float b1r[4], w2r[4];
        #pragma unroll
        for (int nt = 0; nt < 4; nt++){
            b1r[nt] = b1g[nt * 16 + l16];
            w2r[nt] = w2g[nt * 16 + l16];
        }
        bf16x8 av[4];
        #pragma unroll
        for (int ks = 0; ks < 4; ks++){
            const float* p = &g_h[(size_t)(base + l16) * 128 + ks * 32 + quad * 8];
            float4 f0 = *(const float4*)p;
            float4 f1 = *(const float4*)(p + 4);
            union { unsigned int u[4]; bf16x8 v; } pk;
            pk.u[0] = (unsigned int)f2bfbits(f0.x) | ((unsigned int)f2bfbits(f0.y) << 16);
            pk.u[1] = (unsigned int)f2bfbits(f0.z) | ((unsigned int)f2bfbits(f0.w) << 16);
            pk.u[2] = (unsigned int)f2bfbits(f1.x) | ((unsigned int)f2bfbits(f1.y) << 16);
            pk.u[3] = (unsigned int)f2bfbits(f1.z) | ((unsigned int)f2bfbits(f1.w) << 16);
            av[ks] = pk.v;
        }
        f32x4 acc[4] = {};
        #pragma unroll
        for (int nt = 0; nt < 4; nt++){
            int n = nt * 16 + l16;
            #pragma unroll
            for (int ks = 0; ks < 4; ks++){
                bf16x8 bv = *(const bf16x8*)&g_w1hT[n * 128 + ks * 32 + quad * 8];
                acc[nt] = __builtin_amdgcn_mfma_f32_16x16x32_bf16(av[ks], bv, acc[nt], 0, 0, 0);
            }
        }
        float srow[4];
        #pragma unroll
        for (int r = 0; r < 4; r++){
            float s = 0.0f;
            #pragma unroll
            for (int nt = 0; nt < 4; nt++)
                s += sspf_fast(acc[nt][r] + b1r[nt]) * w2r[nt];
            #pragma unroll
            for (int off = 1; off < 16; off <<= 1)
                s += __shfl_xor(s, off, 64);
            srow[r] = s;
        }
        if (l16 == 0){
            #pragma unroll
            for (int r = 0; r < 4; r++){
                int node = base + quad * 4 + r;
                atomicAdd(&part[batch[node]], srow[r] + sb2);
            }
        }
    }
    __syncthreads();
    if (tid < NGRAPHS && part[tid] != 0.0f)
        __hip_atomic_fetch_add(&g_gout[tid], part[tid],
                               __ATOMIC_RELAXED, __HIP_MEMORY_SCOPE_AGENT);
}

__global__ void store_kernel(float* __restrict__ out){
    int i = threadIdx.x;
    if (i < NGRAPHS) out[i] = g_gout[i];
}

extern "C" void kernel_launch(void* const* d_in, const int* in_sizes, int n_in,
                              void* d_out, int out_size, void* d_ws, size_t ws_size,
                              hipStream_t stream)
{
    const int* z       = (const int*)d_in[0];
    const float* pos   = (const float*)d_in[1];
    const int* ei      = (const int*)d_in[2];
    const int* src = ei;
    const int* dst = ei + N_EDGES;
    const int* batch   = (const int*)d_in[3];
    const float* emb     = (const float*)d_in[4];
    const float* mlp_w1  = (const float*)d_in[5];
    const float* mlp_b1  = (const float*)d_in[6];
    const float* mlp_w2  = (const float*)d_in[7];
    const float* mlp_b2  = (const float*)d_in[8];
    const float* conv1_w = (const float*)d_in[9];
    const float* conv2_w = (const float*)d_in[10];
    const float* conv2_b = (const float*)d_in[11];
    const float* lin_w   = (const float*)d_in[12];
    const float* lin_b   = (const float*)d_in[13];
    const float* out1_w  = (const float*)d_in[14];
    const float* out1_b  = (const float*)d_in[15];
    const float* out2_w  = (const float*)d_in[16];
    const float* out2_b  = (const float*)d_in[17];
    (void)d_ws; (void)ws_size; (void)in_sizes; (void)n_in; (void)out_size;

    // --- one-time: CSR sort, tables, weight prep ---
    zero_cnt_kernel<<<196, 256, 0, stream>>>();
    hist_kernel<<<2500, 256, 0, stream>>>(dst);
    scan1_kernel<<<196, 256, 0, stream>>>();
    scan2_kernel<<<1, 256, 0, stream>>>();
    scan3_kernel<<<196, 256, 0, stream>>>();
    scatter_kernel<<<2500, 256, 0, stream>>>(pos, src, dst);
    table_kernel<<<NL * (NT / TPTS), 128, 0, stream>>>(mlp_w1, mlp_b1, mlp_w2, mlp_b2);
    wprep_kernel<<<576, 256, 0, stream>>>(conv1_w, conv2_w, lin_w);
    wprep2_kernel<<<32, 256, 0, stream>>>(out1_w);

    conv1_kernel<<<NTILES, 256, 0, stream>>>(z, emb);  // h init + layer-0 conv1
    for (int l = 0; l < NL; l++){
        agg_kernel<<<6250, 256, 0, stream>>>(l);
        fused_kernel<<<GRID_F2, 256, 0, stream>>>(l, conv2_b + (size_t)l * HID,
                                                  lin_b + (size_t)l * HID, l == NL - 1);
    }

    head_kernel<<<(NWT + 3) / 4, 256, 0, stream>>>(out1_b, out2_w, out2_b, batch);
    store_kernel<<<1, 64, 0, stream>>>((float*)d_out);
}

// Round 18
// 486.389 us; speedup vs baseline: 1.5408x; 1.0104x over previous
//
#include <hip/hip_runtime.h>
#include <math.h>

#define N_NODES 50000
#define N_EDGES 640000
#define HID 128
#define NL 3
#define NGRAPHS 64
#define NT 4096
#define TPTS 8
#define DMAX 1.7330f
#define NPAD 50176   // 196*256
#define NTILES 1563  // ceil(50000/32)
#define NWT 3125     // 50000/16 tiles (exact)

typedef __attribute__((ext_vector_type(8))) short bf16x8;
typedef __attribute__((ext_vector_type(4))) float f32x4;

// ---------------- module-scope device buffers -------------------------------
__device__ __align__(16) float g_h  [N_NODES * HID];           // f32 node features
__device__ __align__(16) unsigned short g_xfb [N_NODES * HID]; // bf16 xf
__device__ __align__(16) unsigned short g_aggb[N_NODES * HID]; // bf16 aggregation
__device__ __align__(16) unsigned short g_table[NL * NT * HID];// bf16 W(d)*C(d), 3 MB
__device__ __align__(16) unsigned short g_wT[9 * HID * HID];   // bf16 [n][k]
__device__ __align__(16) unsigned short g_w1hT[64 * HID];      // bf16 out1_w [n][k]
__device__ __align__(16) int   g_cnt[NPAD];
__device__ __align__(16) int   g_ex [NPAD];
__device__ __align__(16) int   g_row[NPAD];
__device__ __align__(16) int   g_part[256];
__device__ __align__(16) int   g_ssrc[N_EDGES];
__device__ __align__(16) int   g_sidx[N_EDGES];                // nearest table idx
__device__ __align__(16) float g_gout[NGRAPHS];

__device__ __forceinline__ unsigned short f2bfbits(float x){
    union { float f; unsigned int i; } v; v.f = x;
    unsigned int lsb = (v.i >> 16) & 1;
    v.i += 0x7fff + lsb;                      // RNE to bf16
    return (unsigned short)(v.i >> 16);
}
__device__ __forceinline__ float bf2f(unsigned short u){
    union { unsigned int i; float f; } v; v.i = ((unsigned int)u) << 16; return v.f;
}
// exact ShiftedSoftplus (precompute paths)
__device__ __forceinline__ float sspf(float x){
    return fmaxf(x, 0.0f) + log1pf(__expf(-fabsf(x))) - 0.69314718055994530942f;
}
// fast ShiftedSoftplus: ln((1+e^x)/2); exact tails, safe for |x| < 87
__device__ __forceinline__ float sspf_fast(float x){
    return __logf(fmaf(0.5f, __expf(x), 0.5f));
}

// ---------------- counting sort of edges by dst ------------------------------
__global__ __launch_bounds__(256) void zero_cnt_kernel(){
    int i = blockIdx.x * 256 + threadIdx.x;
    g_cnt[i] = 0;                                   // NPAD exact
    if (blockIdx.x == 0 && threadIdx.x < NGRAPHS) g_gout[threadIdx.x] = 0.0f;
}
__global__ __launch_bounds__(256) void hist_kernel(const int* __restrict__ dst){
    int e = blockIdx.x * 256 + threadIdx.x;         // 2500*256 exact
    atomicAdd(&g_cnt[dst[e]], 1);
}
__global__ __launch_bounds__(256) void scan1_kernel(){
    __shared__ int s[256];
    int b = blockIdx.x, t = threadIdx.x, i = b * 256 + t;
    int c = g_cnt[i];
    s[t] = c; __syncthreads();
    #pragma unroll
    for (int off = 1; off < 256; off <<= 1){
        int v = (t >= off) ? s[t - off] : 0; __syncthreads();
        s[t] += v; __syncthreads();
    }
    g_ex[i] = s[t] - c;
    if (t == 255) g_part[b] = s[255];
}
__global__ __launch_bounds__(256) void scan2_kernel(){
    __shared__ int s[256];
    int t = threadIdx.x;
    s[t] = (t < 196) ? g_part[t] : 0; __syncthreads();
    #pragma unroll
    for (int off = 1; off < 256; off <<= 1){
        int v = (t >= off) ? s[t - off] : 0; __syncthreads();
        s[t] += v; __syncthreads();
    }
    g_part[t] = s[t];
}
__global__ __launch_bounds__(256) void scan3_kernel(){
    int b = blockIdx.x, i = b * 256 + threadIdx.x;
    g_row[i] = g_ex[i] + (b > 0 ? g_part[b - 1] : 0);
}
__global__ __launch_bounds__(256) void scatter_kernel(
    const float* __restrict__ pos, const int* __restrict__ src,
    const int* __restrict__ dst)
{
    int e = blockIdx.x * 256 + threadIdx.x;         // exact
    int sv = src[e], dv = dst[e];
    float dx = pos[3*dv]   - pos[3*sv];
    float dy = pos[3*dv+1] - pos[3*sv+1];
    float dz = pos[3*dv+2] - pos[3*sv+2];
    float d = sqrtf(dx*dx + dy*dy + dz*dz);         // < sqrt(3) < DMAX
    int p = atomicAdd(&g_row[dv], 1);               // g_row[v] ends at end-offset
    g_ssrc[p] = sv;
    g_sidx[p] = (int)(d * ((float)(NT - 1) / DMAX) + 0.5f);  // nearest
}

// ---------------- per-layer filter table: 8 points/block, w2 row-reuse ------
__global__ __launch_bounds__(128) void table_kernel(
    const float* __restrict__ w1g, const float* __restrict__ b1g,
    const float* __restrict__ w2g, const float* __restrict__ b2g)
{
    int bid = blockIdx.x;                           // 3 * NT/TPTS blocks
    int l = bid / (NT / TPTS);
    int pt0 = (bid % (NT / TPTS)) * TPTS;
    int n = threadIdx.x;
    __shared__ __align__(16) float w1s[50 * 128];   // 25.6 KB
    __shared__ float ea[TPTS][50];
    __shared__ float tm[TPTS][128];
    __shared__ float Cv[TPTS];
    for (int i = n; i < 50 * 128; i += 128) w1s[i] = w1g[(size_t)l * 50 * 128 + i];
    if (n < 50){
        const float step = 5.0f / 49.0f;
        #pragma unroll
        for (int p = 0; p < TPTS; p++){
            float d = (pt0 + p) * (DMAX / (float)(NT - 1));
            float srel = d * 0.2f;
            float env = expf(1.0f - 1.0f / (1.0f - srel * srel));
            float dd = d - step * (float)n;
            ea[p][n] = expf((-0.5f / (step * step)) * dd * dd) * env;
        }
    }
    if (n < TPTS){
        float d = (pt0 + n) * (DMAX / (float)(NT - 1));
        Cv[n] = 0.5f * (cosf(d * 0.62831853071795864769f) + 1.0f);
    }
    __syncthreads();
    float b1v = b1g[l * 128 + n];
    #pragma unroll
    for (int p = 0; p < TPTS; p++){
        float acc = b1v;
        #pragma unroll 10
        for (int k = 0; k < 50; k++) acc = fmaf(ea[p][k], w1s[k * 128 + n], acc);
        tm[p][n] = sspf(acc);
    }
    __syncthreads();
    float b2v = b2g[l * 128 + n];
    float acc2[TPTS];
    #pragma unroll
    for (int p = 0; p < TPTS; p++) acc2[p] = b2v;
    const float* w2 = w2g + (size_t)l * 128 * 128;
    for (int k = 0; k < 128; k++){
        float wv = w2[k * 128 + n];                 // 1 global read, 8 FMA reuse
        #pragma unroll
        for (int p = 0; p < TPTS; p++) acc2[p] = fmaf(tm[p][k], wv, acc2[p]);
    }
    #pragma unroll
    for (int p = 0; p < TPTS; p++)
        g_table[((size_t)l * NT + pt0 + p) * 128 + n] = f2bfbits(acc2[p] * Cv[p]);
}

// ---------------- weight prep: bf16 transpose of 9 node matrices ------------
__global__ __launch_bounds__(256) void wprep_kernel(
    const float* __restrict__ c1, const float* __restrict__ c2,
    const float* __restrict__ lwp)
{
    int gid = blockIdx.x * 256 + threadIdx.x;       // 576*256 = 147456 exact
    int mat = gid >> 14, r = gid & 16383;
    int n = r & 127, k = r >> 7;
    int l = mat / 3, w = mat % 3;
    const float* base = (w == 0 ? c1 : w == 1 ? c2 : lwp) + (size_t)l * HID * HID;
    g_wT[(size_t)mat * HID * HID + n * 128 + k] = f2bfbits(base[k * 128 + n]);
}

// out1_w [128][64] -> bf16 [n=64][k=128]
__global__ __launch_bounds__(256) void wprep2_kernel(const float* __restrict__ w1g){
    int gid = blockIdx.x * 256 + threadIdx.x;       // 32*256 = 8192 exact
    int n = gid & 63, k = gid >> 6;
    g_w1hT[n * 128 + k] = f2bfbits(w1g[k * 64 + n]);
}

// ---------------- layer-0 conv1: emb gather + h init + GEMM -----------------
__global__ __launch_bounds__(256) void conv1_kernel(
    const int* __restrict__ z, const float* __restrict__ emb)
{
    __shared__ __align__(16) unsigned short a_s[32 * 128];    // 8 KB
    __shared__ int zl[32];
    int tid = threadIdx.x;
    int wave = tid >> 6, lane = tid & 63, quad = lane >> 4, l16 = lane & 15;
    int mtile = (wave & 1) * 16, nbase = (wave >> 1) * 64;
    for (int t = blockIdx.x; t < NTILES; t += gridDim.x){
        int base = t * 32;
        __syncthreads();
        if (tid < 32) zl[tid] = (base + tid < N_NODES) ? z[base + tid] : 0;
        __syncthreads();
        for (int i = tid; i < 512; i += 256){
            int nn = i >> 4, c = i & 15, node = base + nn;
            int phys = c ^ (nn & 15);
            uint4 q = {0u, 0u, 0u, 0u};
            if (node < N_NODES){
                const float* p = &emb[(size_t)zl[nn] * 128 + c * 8];
                float4 f0 = *(const float4*)p;
                float4 f1 = *(const float4*)(p + 4);
                *(float4*)&g_h[(size_t)node * 128 + c * 8]     = f0;
                *(float4*)&g_h[(size_t)node * 128 + c * 8 + 4] = f1;
                q.x = (unsigned int)f2bfbits(f0.x) | ((unsigned int)f2bfbits(f0.y) << 16);
                q.y = (unsigned int)f2bfbits(f0.z) | ((unsigned int)f2bfbits(f0.w) << 16);
                q.z = (unsigned int)f2bfbits(f1.x) | ((unsigned int)f2bfbits(f1.y) << 16);
                q.w = (unsigned int)f2bfbits(f1.z) | ((unsigned int)f2bfbits(f1.w) << 16);
            }
            *(uint4*)&a_s[nn * 128 + phys * 8] = q;
        }
        __syncthreads();
        bf16x8 av[4];
        int arow = mtile + l16;
        #pragma unroll
        for (int ks = 0; ks < 4; ks++){
            int phys = (ks * 4 + quad) ^ (arow & 15);
            av[ks] = *(const bf16x8*)&a_s[arow * 128 + phys * 8];
        }
        f32x4 acc[4] = {};
        #pragma unroll
        for (int nt = 0; nt < 4; nt++){
            int n = nbase + nt * 16 + l16;
            #pragma unroll
            for (int ks = 0; ks < 4; ks++){
                bf16x8 bv = *(const bf16x8*)&g_wT[n * 128 + ks * 32 + quad * 8];
                acc[nt] = __builtin_amdgcn_mfma_f32_16x16x32_bf16(av[ks], bv, acc[nt], 0, 0, 0);
            }
        }
        #pragma unroll
        for (int nt = 0; nt < 4; nt++){
            int n = nbase + nt * 16 + l16;
            #pragma unroll
            for (int r = 0; r < 4; r++){
                int node = base + mtile + quad * 4 + r;
                if (node < N_NODES)
                    g_xfb[(size_t)node * 128 + n] = f2bfbits(acc[nt][r]);
            }
        }
    }
}

// ---------------- fused GEMM chain: column-split, 2 waves per 16-node tile --
// Each wave owns output cols [wave*64, wave*64+64): per-wave weight stream is
// 3 x 16 KB (half of the 1-tile version) while wave count doubles to 6250.
// Two cheap 2-wave barriers exchange t / hb through 8 KB LDS.
__global__ __launch_bounds__(128) void fused_kernel(
    int l, const float* __restrict__ bias2, const float* __restrict__ biasl,
    int skip3)
{
    __shared__ __align__(16) unsigned short ts [16 * 128];   // 4 KB t tile
    __shared__ __align__(16) unsigned short ts2[16 * 128];   // 4 KB hb tile
    int tid = threadIdx.x;
    int wave = tid >> 6, lane = tid & 63, quad = lane >> 4, l16 = lane & 15;
    int nbase = wave * 64;
    const unsigned short* c2  = g_wT + (size_t)(l * 3 + 1) * HID * HID;
    const unsigned short* lw  = g_wT + (size_t)(l * 3 + 2) * HID * HID;
    const unsigned short* c1n = g_wT + (size_t)((l + 1) * 3) * HID * HID;

    int base = blockIdx.x * 16;                // 3125 blocks, exact

    float b2r[4], blr[4];
    #pragma unroll
    for (int nt = 0; nt < 4; nt++){
        b2r[nt] = bias2[nbase + nt * 16 + l16];
        blr[nt] = biasl[nbase + nt * 16 + l16];
    }

    // ---- GEMM1: acc = aggb(tile) @ c2[:, nbase:nbase+64]
    bf16x8 av[4];
    #pragma unroll
    for (int ks = 0; ks < 4; ks++)
        av[ks] = *(const bf16x8*)&g_aggb[(size_t)(base + l16) * 128 + ks * 32 + quad * 8];
    f32x4 acc[4] = {};
    #pragma unroll
    for (int nt = 0; nt < 4; nt++){
        int n = nbase + nt * 16 + l16;
        #pragma unroll
        for (int ks = 0; ks < 4; ks++){
            bf16x8 bv = *(const bf16x8*)&c2[n * 128 + ks * 32 + quad * 8];
            acc[nt] = __builtin_amdgcn_mfma_f32_16x16x32_bf16(av[ks], bv, acc[nt], 0, 0, 0);
        }
    }
    // epilogue1: t = ssp(acc + b2) -> ts (swizzled)
    #pragma unroll
    for (int nt = 0; nt < 4; nt++){
        int col = nbase + nt * 16 + l16;
        int c = col >> 3, sub = col & 7;
        #pragma unroll
        for (int r = 0; r < 4; r++){
            int row = quad * 4 + r;
            ts[row * 128 + ((c ^ row) & 15) * 8 + sub] =
                f2bfbits(sspf_fast(acc[nt][r] + b2r[nt]));
        }
    }
    __syncthreads();                            // t complete (2 waves)

    // ---- GEMM2: acc2 = t @ lw[:, nbase:nbase+64]
    #pragma unroll
    for (int ks = 0; ks < 4; ks++){
        int phys = ((ks * 4 + quad) ^ l16) & 15;
        av[ks] = *(const bf16x8*)&ts[l16 * 128 + phys * 8];
    }
    f32x4 acc2[4] = {};
    #pragma unroll
    for (int nt = 0; nt < 4; nt++){
        int n = nbase + nt * 16 + l16;
        #pragma unroll
        for (int ks = 0; ks < 4; ks++){
            bf16x8 bv = *(const bf16x8*)&lw[n * 128 + ks * 32 + quad * 8];
            acc2[nt] = __builtin_amdgcn_mfma_f32_16x16x32_bf16(av[ks], bv, acc2[nt], 0, 0, 0);
        }
    }
    // epilogue2: h += acc2 + lb; stash bf16(h) into ts2 for GEMM3
    #pragma unroll
    for (int nt = 0; nt < 4; nt++){
        int col = nbase + nt * 16 + l16;
        int c = col >> 3, sub = col & 7;
        #pragma unroll
        for (int r = 0; r < 4; r++){
            int row = quad * 4 + r;
            size_t o = (size_t)(base + row) * 128 + col;
            float hv = g_h[o] + acc2[nt][r] + blr[nt];
            g_h[o] = hv;
            if (!skip3)
                ts2[row * 128 + ((c ^ row) & 15) * 8 + sub] = f2bfbits(hv);
        }
    }
    if (skip3) return;
    __syncthreads();                            // hb complete (2 waves)

    // ---- GEMM3: xfb = bf16(h) @ c1next[:, nbase:nbase+64]
    #pragma unroll
    for (int ks = 0; ks < 4; ks++){
        int phys = ((ks * 4 + quad) ^ l16) & 15;
        av[ks] = *(const bf16x8*)&ts2[l16 * 128 + phys * 8];
    }
    f32x4 acc3[4] = {};
    #pragma unroll
    for (int nt = 0; nt < 4; nt++){
        int n = nbase + nt * 16 + l16;
        #pragma unroll
        for (int ks = 0; ks < 4; ks++){
            bf16x8 bv = *(const bf16x8*)&c1n[n * 128 + ks * 32 + quad * 8];
            acc3[nt] = __builtin_amdgcn_mfma_f32_16x16x32_bf16(av[ks], bv, acc3[nt], 0, 0, 0);
        }
    }
    #pragma unroll
    for (int nt = 0; nt < 4; nt++){
        int col = nbase + nt * 16 + l16;
        #pragma unroll
        for (int r = 0; r < 4; r++){
            int row = quad * 4 + r;
            g_xfb[(size_t)(base + row) * 128 + col] = f2bfbits(acc3[nt][r]);
        }
    }
}

// ---------------- CSR edge aggregation: bf16 nearest-table, 4-edge unroll ---
__global__ __launch_bounds__(256) void agg_kernel(int l){
    const unsigned short* __restrict__ T = g_table + (size_t)l * NT * 128;
    int tid = threadIdx.x;
    int grp = tid >> 5, n0 = (tid & 31) * 4;
    int v = blockIdx.x * 8 + grp;                   // 6250 blocks * 8 = 50000 exact
    int e1 = g_row[v];
    int e0 = e1 - g_cnt[v];
    float a0 = 0.f, a1 = 0.f, a2 = 0.f, a3 = 0.f;
    int j = e0;
    for (; j + 4 <= e1; j += 4){
        int sA = g_ssrc[j],   sB = g_ssrc[j+1];
        int sC = g_ssrc[j+2], sD = g_ssrc[j+3];
        int iA = g_sidx[j],   iB = g_sidx[j+1];
        int iC = g_sidx[j+2], iD = g_sidx[j+3];
        ushort4 tA = *(const ushort4*)&T[(size_t)iA * 128 + n0];
        ushort4 tB = *(const ushort4*)&T[(size_t)iB * 128 + n0];
        ushort4 tC = *(const ushort4*)&T[(size_t)iC * 128 + n0];
        ushort4 tD = *(const ushort4*)&T[(size_t)iD * 128 + n0];
        ushort4 gA = *(const ushort4*)&g_xfb[(size_t)sA * 128 + n0];
        ushort4 gB = *(const ushort4*)&g_xfb[(size_t)sB * 128 + n0];
        ushort4 gC = *(const ushort4*)&g_xfb[(size_t)sC * 128 + n0];
        ushort4 gD = *(const ushort4*)&g_xfb[(size_t)sD * 128 + n0];
        a0 = fmaf(bf2f(tA.x), bf2f(gA.x), a0); a1 = fmaf(bf2f(tA.y), bf2f(gA.y), a1);
        a2 = fmaf(bf2f(tA.z), bf2f(gA.z), a2); a3 = fmaf(bf2f(tA.w), bf2f(gA.w), a3);
        a0 = fmaf(bf2f(tB.x), bf2f(gB.x), a0); a1 = fmaf(bf2f(tB.y), bf2f(gB.y), a1);
        a2 = fmaf(bf2f(tB.z), bf2f(gB.z), a2); a3 = fmaf(bf2f(tB.w), bf2f(gB.w), a3);
        a0 = fmaf(bf2f(tC.x), bf2f(gC.x), a0); a1 = fmaf(bf2f(tC.y), bf2f(gC.y), a1);
        a2 = fmaf(bf2f(tC.z), bf2f(gC.z), a2); a3 = fmaf(bf2f(tC.w), bf2f(gC.w), a3);
        a0 = fmaf(bf2f(tD.x), bf2f(gD.x), a0); a1 = fmaf(bf2f(tD.y), bf2f(gD.y), a1);
        a2 = fmaf(bf2f(tD.z), bf2f(gD.z), a2); a3 = fmaf(bf2f(tD.w), bf2f(gD.w), a3);
    }
    for (; j < e1; j++){
        int s = g_ssrc[j], i0 = g_sidx[j];
        ushort4 t0 = *(const ushort4*)&T[(size_t)i0 * 128 + n0];
        ushort4 g = *(const ushort4*)&g_xfb[(size_t)s * 128 + n0];
        a0 = fmaf(bf2f(t0.x), bf2f(g.x), a0); a1 = fmaf(bf2f(t0.y), bf2f(g.y), a1);
        a2 = fmaf(bf2f(t0.z), bf2f(g.z), a2); a3 = fmaf(bf2f(t0.w), bf2f(g.w), a3);
    }
    ushort4 o;
    o.x = f2bfbits(a0); o.y = f2bfbits(a1); o.z = f2bfbits(a2); o.w = f2bfbits(a3);
    *(ushort4*)&g_aggb[(size_t)v * 128 + n0] = o;
}

// ---------------- output head: MFMA GEMM + quad-butterfly + seg-sum ---------
__global__ __launch_bounds__(256) void head_kernel(
    const float* __restrict__ b1g, const float* __restrict__ w2g,
    const float* __restrict__ b2g, const int* __restrict__ batch)
{
    __shared__ float part[NGRAPHS];
    int tid = threadIdx.x;
    int wave = tid >> 6, lane = tid & 63, quad = lane >> 4, l16 = lane & 15;
    if (tid < NGRAPHS) part[tid] = 0.0f;
    __syncthreads();
    float sb2 = b2g[0];

    int wt = blockIdx.x * 4 + wave;            // 782 blocks; 50000 = 3125*16 exact
    if (wt < NWT){
        int base = wt * 16;
        float b1r[4], w2r[4];
        #pragma unroll
        for (int nt = 0; nt < 4; nt++){
            b1r[nt] = b1g[nt * 16 + l16];
            w2r[nt] = w2g[nt * 16 + l16];
        }
        bf16x8 av[4];
        #pragma unroll
        for (int ks = 0; ks < 4; ks++){
            const float* p = &g_h[(size_t)(base + l16) * 128 + ks * 32 + quad * 8];
            float4 f0 = *(const float4*)p;
            float4 f1 = *(const float4*)(p + 4);
            union { unsigned int u[4]; bf16x8 v; } pk;
            pk.u[0] = (unsigned int)f2bfbits(f0.x) | ((unsigned int)f2bfbits(f0.y) << 16);
            pk.u[1] = (unsigned int)f2bfbits(f0.z) | ((unsigned int)f2bfbits(f0.w) << 16);
            pk.u[2] = (unsigned int)f2bfbits(f1.x) | ((unsigned int)f2bfbits(f1.y) << 16);
            pk.u[3] = (unsigned int)f2bfbits(f1.z) | ((unsigned int)f2bfbits(f1.w) << 16);
            av[ks] = pk.v;
        }
        f32x4 acc[4] = {};
        #pragma unroll
        for (int nt = 0; nt < 4; nt++){
            int n = nt * 16 + l16;
            #pragma unroll
            for (int ks = 0; ks < 4; ks++){
                bf16x8 bv = *(const bf16x8*)&g_w1hT[n * 128 + ks * 32 + quad * 8];
                acc[nt] = __builtin_amdgcn_mfma_f32_16x16x32_bf16(av[ks], bv, acc[nt], 0, 0, 0);
            }
        }
        float srow[4];
        #pragma unroll
        for (int r = 0; r < 4; r++){
            float s = 0.0f;
            #pragma unroll
            for (int nt = 0; nt < 4; nt++)
                s += sspf_fast(acc[nt][r] + b1r[nt]) * w2r[nt];
            #pragma unroll
            for (int off = 1; off < 16; off <<= 1)
                s += __shfl_xor(s, off, 64);
            srow[r] = s;
        }
        if (l16 == 0){
            #pragma unroll
            for (int r = 0; r < 4; r++){
                int node = base + quad * 4 + r;
                atomicAdd(&part[batch[node]], srow[r] + sb2);
            }
        }
    }
    __syncthreads();
    if (tid < NGRAPHS && part[tid] != 0.0f)
        __hip_atomic_fetch_add(&g_gout[tid], part[tid],
                               __ATOMIC_RELAXED, __HIP_MEMORY_SCOPE_AGENT);
}

__global__ void store_kernel(float* __restrict__ out){
    int i = threadIdx.x;
    if (i < NGRAPHS) out[i] = g_gout[i];
}

extern "C" void kernel_launch(void* const* d_in, const int* in_sizes, int n_in,
                              void* d_out, int out_size, void* d_ws, size_t ws_size,
                              hipStream_t stream)
{
    const int* z       = (const int*)d_in[0];
    const float* pos   = (const float*)d_in[1];
    const int* ei      = (const int*)d_in[2];
    const int* src = ei;
    const int* dst = ei + N_EDGES;
    const int* batch   = (const int*)d_in[3];
    const float* emb     = (const float*)d_in[4];
    const float* mlp_w1  = (const float*)d_in[5];
    const float* mlp_b1  = (const float*)d_in[6];
    const float* mlp_w2  = (const float*)d_in[7];
    const float* mlp_b2  = (const float*)d_in[8];
    const float* conv1_w = (const float*)d_in[9];
    const float* conv2_w = (const float*)d_in[10];
    const float* conv2_b = (const float*)d_in[11];
    const float* lin_w   = (const float*)d_in[12];
    const float* lin_b   = (const float*)d_in[13];
    const float* out1_w  = (const float*)d_in[14];
    const float* out1_b  = (const float*)d_in[15];
    const float* out2_w  = (const float*)d_in[16];
    const float* out2_b  = (const float*)d_in[17];
    (void)d_ws; (void)ws_size; (void)in_sizes; (void)n_in; (void)out_size;

    // --- one-time: CSR sort, tables, weight prep ---
    zero_cnt_kernel<<<196, 256, 0, stream>>>();
    hist_kernel<<<2500, 256, 0, stream>>>(dst);
    scan1_kernel<<<196, 256, 0, stream>>>();
    scan2_kernel<<<1, 256, 0, stream>>>();
    scan3_kernel<<<196, 256, 0, stream>>>();
    scatter_kernel<<<2500, 256, 0, stream>>>(pos, src, dst);
    table_kernel<<<NL * (NT / TPTS), 128, 0, stream>>>(mlp_w1, mlp_b1, mlp_w2, mlp_b2);
    wprep_kernel<<<576, 256, 0, stream>>>(conv1_w, conv2_w, lin_w);
    wprep2_kernel<<<32, 256, 0, stream>>>(out1_w);

    conv1_kernel<<<NTILES, 256, 0, stream>>>(z, emb);  // h init + layer-0 conv1
    for (int l = 0; l < NL; l++){
        agg_kernel<<<6250, 256, 0, stream>>>(l);
        fused_kernel<<<NWT, 128, 0, stream>>>(l, conv2_b + (size_t)l * HID,
                                              lin_b + (size_t)l * HID, l == NL - 1);
    }

    head_kernel<<<(NWT + 3) / 4, 256, 0, stream>>>(out1_b, out2_w, out2_b, batch);
    store_kernel<<<1, 64, 0, stream>>>((float*)d_out);
}